// Round 7
// baseline (9431.931 us; speedup 1.0000x reference)
//
#include <hip/hip_runtime.h>
#include <stdint.h>

#define DD 1024   // D
#define SS 1024   // S
#define NBS 32    // scan blocks (co-resident: 32 <= 256 CUs)

typedef __attribute__((ext_vector_type(8))) __bf16 bf16x8;
typedef __attribute__((ext_vector_type(4))) float f32x4;

union Frag { uint4 u; bf16x8 b; };

__device__ __forceinline__ float bf2f(ushort u){ union{uint32_t i; float f;} c; c.i = ((uint32_t)u)<<16; return c.f; }
__device__ __forceinline__ float bflo(uint32_t p){ union{uint32_t i; float f;} c; c.i = p<<16; return c.f; }
__device__ __forceinline__ float bfhi(uint32_t p){ union{uint32_t i; float f;} c; c.i = p & 0xffff0000u; return c.f; }
__device__ __forceinline__ ushort f2bf(float f){
  union{float f; uint32_t u;} c; c.f = f;
  uint32_t u = c.u;
  return (ushort)((u + 0x7fffu + ((u>>16)&1u)) >> 16);   // RNE
}

// ------------------------------------------------------------------- cast ---
__global__ __launch_bounds__(256) void cast_k(const float* __restrict__ s,
    ushort* __restrict__ d, int n)
{
  int i = (blockIdx.x*256 + threadIdx.x)*4;
  if (i >= n) return;
  float4 v = *(const float4*)(s+i);
  ushort4 o; o.x=f2bf(v.x); o.y=f2bf(v.y); o.z=f2bf(v.z); o.w=f2bf(v.w);
  *(ushort4*)(d+i) = o;
}

// ---------------------------------------------------------------- rmsnorm ---
__global__ __launch_bounds__(256) void rmsnorm_k(const float* __restrict__ X,
    const float* __restrict__ w, ushort* __restrict__ out)
{
  const int row = blockIdx.x, t = threadIdx.x;
  const float* x = X + (size_t)row*DD;
  float xs[4]; float s = 0.f;
  #pragma unroll
  for (int i=0;i<4;i++){ float v = x[t + i*256]; xs[i]=v; s += v*v; }
  #pragma unroll
  for (int off=32; off>0; off>>=1) s += __shfl_xor(s, off, 64);
  __shared__ float sred[4];
  if ((t&63)==0) sred[t>>6] = s;
  __syncthreads();
  s = sred[0]+sred[1]+sred[2]+sred[3];
  float inv = 1.f/(sqrtf(s)*0.03125f + 1e-6f);   // /sqrt(1024), + eps
  #pragma unroll
  for (int i=0;i<4;i++){
    int c2 = t + i*256;
    out[(size_t)row*DD + c2] = f2bf(xs[i]*inv*w[c2]);
  }
}

// ---------------------------------------------------------- MFMA GEMM (BT) --
enum { ACT_NONE=0, ACT_RELU=1, ACT_SIG=2, ACT_GELU=3 };
enum { EPI_B16=0, EPI_DUAL=1, EPI_F32=2, EPI_Y=3, EPI_OUT=4 };

template<int ACT, int EPI>
__global__ __launch_bounds__(256) void gemm_bt(
    const ushort* __restrict__ A, const ushort* __restrict__ W,
    const float* __restrict__ bias, int N, int K,
    ushort* __restrict__ Ob, float* __restrict__ Of,
    const float* __restrict__ X32, const ushort* __restrict__ H16,
    const float* __restrict__ Yf)
{
  __shared__ __align__(16) ushort At[128*32];
  __shared__ __align__(16) ushort Wt[128*32];
  const int tid = threadIdx.x;
  const int wave = tid >> 6, lane = tid & 63;
  const int quad = lane >> 4, l16 = lane & 15;
  const int wr = wave >> 1, wc = wave & 1;
  const int m0 = blockIdx.x * 128, n0 = blockIdx.y * 128;

  f32x4 acc[4][4];
  const f32x4 vz = {0.f,0.f,0.f,0.f};
  #pragma unroll
  for (int i=0;i<4;i++)
    #pragma unroll
    for (int j=0;j<4;j++) acc[i][j] = vz;

  const ushort* gA = A + (size_t)(m0 + wave*32 + (lane>>2))*K + (lane&3)*8;
  const ushort* gW = W + (size_t)(n0 + wave*32 + (lane>>2))*K + (lane&3)*8;
  ushort* lA = At + wave*1024 + lane*8;
  ushort* lW = Wt + wave*1024 + lane*8;

  for (int ko = 0; ko < K; ko += 32) {
    uint4 va  = *(const uint4*)(gA + ko);
    uint4 va2 = *(const uint4*)(gA + ko + (size_t)16*K);
    uint4 vw  = *(const uint4*)(gW + ko);
    uint4 vw2 = *(const uint4*)(gW + ko + (size_t)16*K);
    __syncthreads();
    *(uint4*)lA          = va;
    *(uint4*)(lA + 512)  = va2;
    *(uint4*)lW          = vw;
    *(uint4*)(lW + 512)  = vw2;
    __syncthreads();
    Frag af[4], bfr[4];
    #pragma unroll
    for (int mi=0;mi<4;mi++)
      af[mi].u = *(const uint4*)&At[(wr*64 + mi*16 + l16)*32 + quad*8];
    #pragma unroll
    for (int ni=0;ni<4;ni++)
      bfr[ni].u = *(const uint4*)&Wt[(wc*64 + ni*16 + l16)*32 + quad*8];
    #pragma unroll
    for (int mi=0;mi<4;mi++)
      #pragma unroll
      for (int ni=0;ni<4;ni++)
        acc[mi][ni] = __builtin_amdgcn_mfma_f32_16x16x32_bf16(af[mi].b, bfr[ni].b, acc[mi][ni], 0,0,0);
  }

  float bia[4];
  #pragma unroll
  for (int ni=0;ni<4;ni++) bia[ni] = bias[n0 + wc*64 + ni*16 + l16];
  #pragma unroll
  for (int mi=0;mi<4;mi++) {
    const int row0 = m0 + wr*64 + mi*16 + quad*4;
    #pragma unroll
    for (int ni=0;ni<4;ni++) {
      const int col = n0 + wc*64 + ni*16 + l16;
      #pragma unroll
      for (int r=0;r<4;r++) {
        float vx = acc[mi][ni][r] + bia[ni];
        if (ACT == ACT_RELU) vx = fmaxf(vx, 0.f);
        else if (ACT == ACT_SIG) {
          vx = 1.f/(1.f+__expf(-vx));
          vx = fminf(fmaxf(vx, 1e-6f), 1.f-1e-6f);
        } else if (ACT == ACT_GELU) {
          float ci = 0.7978845608028654f*(vx + 0.044715f*vx*vx*vx);
          float th = 1.f - 2.f/(1.f + __expf(2.f*ci));
          vx = 0.5f*vx*(1.f+th);
        }
        size_t idx = (size_t)(row0 + r)*N + col;
        if (EPI == EPI_B16)      Ob[idx] = f2bf(vx);
        else if (EPI == EPI_DUAL){ Ob[idx] = f2bf(vx); Of[idx] = vx; }
        else if (EPI == EPI_F32)  Of[idx] = vx;
        else if (EPI == EPI_Y)    Of[idx] = vx + X32[idx] + bf2f(H16[idx]);
        else                      Of[idx] = vx + Yf[idx];
      }
    }
  }
}

// ------------------------------------------------------------- attention ----
__global__ __launch_bounds__(256) void attn_k(const ushort* __restrict__ q,
  const ushort* __restrict__ k, const ushort* __restrict__ v, ushort* __restrict__ ao)
{
  __shared__ __align__(16) ushort Ks[64*64];
  __shared__ __align__(16) ushort Vs[64*64];
  __shared__ float Ps[64*65];
  const int qt = blockIdx.x, bh = blockIdx.y;
  const int b = bh >> 4, h = bh & 15;
  const int t = threadIdx.x, r = t >> 2, seg = t & 3;
  const ushort* qrow = q + ((size_t)(b*SS + qt*64 + r))*DD + h*64;
  float qr[64];
  #pragma unroll
  for (int i=0;i<64;i+=8){
    uint4 u = *(const uint4*)(qrow + i);
    qr[i+0]=bflo(u.x); qr[i+1]=bfhi(u.x); qr[i+2]=bflo(u.y); qr[i+3]=bfhi(u.y);
    qr[i+4]=bflo(u.z); qr[i+5]=bfhi(u.z); qr[i+6]=bflo(u.w); qr[i+7]=bfhi(u.w);
  }
  float o[16];
  #pragma unroll
  for (int i=0;i<16;i++) o[i]=0.f;
  float mrun = -1e30f, lrun = 0.f;
  const int jrow = t >> 3, jch = t & 7;
  for (int kt=0; kt<16; kt++) {
    __syncthreads();
    const ushort* kg = k + ((size_t)(b*SS + kt*64))*DD + h*64;
    const ushort* vg = v + ((size_t)(b*SS + kt*64))*DD + h*64;
    #pragma unroll
    for (int part=0; part<2; part++){
      int j = jrow + part*32;
      *(uint4*)&Ks[j*64 + jch*8] = *(const uint4*)(kg + (size_t)j*DD + jch*8);
      *(uint4*)&Vs[j*64 + jch*8] = *(const uint4*)(vg + (size_t)j*DD + jch*8);
    }
    __syncthreads();
    float sc[16];
    #pragma unroll
    for (int jj=0;jj<16;jj++){
      int j = seg*16 + jj;
      float s_ = 0.f;
      #pragma unroll
      for (int i=0;i<64;i+=8){
        uint4 u = *(const uint4*)&Ks[j*64+i];
        s_ = fmaf(qr[i+0], bflo(u.x), s_); s_ = fmaf(qr[i+1], bfhi(u.x), s_);
        s_ = fmaf(qr[i+2], bflo(u.y), s_); s_ = fmaf(qr[i+3], bfhi(u.y), s_);
        s_ = fmaf(qr[i+4], bflo(u.z), s_); s_ = fmaf(qr[i+5], bfhi(u.z), s_);
        s_ = fmaf(qr[i+6], bflo(u.w), s_); s_ = fmaf(qr[i+7], bfhi(u.w), s_);
      }
      sc[jj] = s_ * 0.125f;
    }
    float mx = sc[0];
    #pragma unroll
    for (int jj=1;jj<16;jj++) mx = fmaxf(mx, sc[jj]);
    mx = fmaxf(mx, __shfl_xor(mx, 1, 64));
    mx = fmaxf(mx, __shfl_xor(mx, 2, 64));
    float mnew = fmaxf(mrun, mx);
    float psum = 0.f;
    #pragma unroll
    for (int jj=0;jj<16;jj++){
      float p = __expf(sc[jj]-mnew);
      Ps[r*65 + seg*16 + jj] = p;
      psum += p;
    }
    psum += __shfl_xor(psum, 1, 64);
    psum += __shfl_xor(psum, 2, 64);
    float alpha = __expf(mrun - mnew);
    lrun = lrun*alpha + psum;
    mrun = mnew;
    #pragma unroll
    for (int i=0;i<16;i++) o[i] *= alpha;
    __syncthreads();
    #pragma unroll 4
    for (int j=0;j<64;j++){
      float pj = Ps[r*65 + j];
      uint4 u0 = *(const uint4*)&Vs[j*64 + seg*16];
      uint4 u1 = *(const uint4*)&Vs[j*64 + seg*16 + 8];
      o[ 0]=fmaf(pj,bflo(u0.x),o[ 0]); o[ 1]=fmaf(pj,bfhi(u0.x),o[ 1]);
      o[ 2]=fmaf(pj,bflo(u0.y),o[ 2]); o[ 3]=fmaf(pj,bfhi(u0.y),o[ 3]);
      o[ 4]=fmaf(pj,bflo(u0.z),o[ 4]); o[ 5]=fmaf(pj,bfhi(u0.z),o[ 5]);
      o[ 6]=fmaf(pj,bflo(u0.w),o[ 6]); o[ 7]=fmaf(pj,bfhi(u0.w),o[ 7]);
      o[ 8]=fmaf(pj,bflo(u1.x),o[ 8]); o[ 9]=fmaf(pj,bfhi(u1.x),o[ 9]);
      o[10]=fmaf(pj,bflo(u1.y),o[10]); o[11]=fmaf(pj,bfhi(u1.y),o[11]);
      o[12]=fmaf(pj,bflo(u1.z),o[12]); o[13]=fmaf(pj,bfhi(u1.z),o[13]);
      o[14]=fmaf(pj,bflo(u1.w),o[14]); o[15]=fmaf(pj,bfhi(u1.w),o[15]);
    }
  }
  float invl = 1.f/lrun;
  ushort* orow = ao + ((size_t)(b*SS + qt*64 + r))*DD + h*64 + seg*16;
  #pragma unroll
  for (int i=0;i<16;i++) orow[i] = f2bf(o[i]*invl);
}

// ----------------------------------------------------------------- scan -----
// h_t = z_t * sigmoid(Wg h_{t-1} + bg) + gamma_t * h_{t-1}.
// Round-15: back to P=32 (R14 falsified fewer-blocks; R14 also spilled a[]),
// with an O(1)-POLL COUNTER PROTOCOL replacing data-polling:
//  Theory: the old poll = 32768 un-coalescable atomic-load ops/sweep through
//  the MALL atomic pipe -> thousands of cycles per sweep (R12: more in-flight
//  atomics = worse; R13: per-sweep inv+refetch = worse). Fix: poll ONE line.
//  - Producers: h data stores stay relaxed-agent-atomic qwords (3x-proven
//    visibility); hseq stores also atomic qwords (keeps L2 free of dirty
//    lines); then ONE RELEASE fetch_add(cnt[slot], 16) per epi wave (lane 0)
//    -- release orders the wave's prior stores (hw drains vmcnt first).
//  - Consumers: all lanes poll cnt[slot] (wave-uniform address = 1 memory
//    request per wave per sweep; 128/sweep chip-wide vs 32768), then ONE
//    acquire-agent fence (buffer_inv; R13-proven builtin) per step, then
//    PLAIN coalesced 32B/lane loads of the 8KB state (post-inv = MALL-fresh).
//  - Monotonic 8-slot counter ring: slot st&7, target 1024*((st>>3)+1).
//    No sentinels, no re-sentinel stores, no ring memset; state depth 2.
//    Depth-2 safety: a block at st+2 passed poll(st+1), which required every
//    block's stores of st+1, which happen after their reads of h(st).
//  - Self-disarming guard (4096 sweeps once, then 1 sweep/step -> NaN fast
//    fail, provably no hang). z/gamma prefetch issued AFTER the release add
//    so its L3 latency is never inside the release drain.
__global__ __launch_bounds__(256) void scan_k(
    const ushort* __restrict__ Wgb, const float* __restrict__ bg,
    const float* __restrict__ z32, const float* __restrict__ gm32,
    ushort* __restrict__ hseq, ushort* __restrict__ hstate, // 2 x [4][1024] bf16
    uint32_t* __restrict__ cnt)                             // 8 slots x 16 dw
{
  const int blk = blockIdx.x, t = threadIdx.x;
  const int wave = t>>6, lane = t&63, quad = lane>>4, c = lane&15;
  const int mt = wave & 1, kh = wave >> 1;
  const int nbase = blk*32 + mt*16;
  const bool epi = (kh == 0) && (c < 4);
  const int n0w = nbase + quad*4;
  Frag a[16];                                   // Wg A-frags, loop-invariant
  {
    const ushort* wrow = Wgb + (size_t)(nbase + c)*DD + kh*512 + quad*8;
    #pragma unroll
    for (int kt=0;kt<16;kt++) a[kt].u = *(const uint4*)(wrow + kt*32);
  }
  float bgv[4];
  #pragma unroll
  for (int r=0;r<4;r++) bgv[r] = bg[nbase + quad*4 + r];
  __shared__ __align__(16) ushort Hs[2][4096];  // double-buffered h_{t-1}
  __shared__ float redbuf[2][64][5];
  const int qi = (c*1024 + n0w) >> 2;           // this lane's h slice (qword)
  int gmax = 4096;                              // poll budget; 0 after a trip

  // prologue: z/gamma for step 0 in flight
  float4 znx = {0,0,0,0}, gnx = {0,0,0,0};
  if (epi) {
    znx = *(const float4*)(z32  + ((size_t)c*SS + 0)*DD + n0w);
    gnx = *(const float4*)(gm32 + ((size_t)c*SS + 0)*DD + n0w);
  }

  for (int st=0; st<SS; st++) {
    const int cur = st & 1;
    if (st > 0) {
      // O(1) poll: one counter line; wave-uniform address
      const uint32_t tgt = ((uint32_t)((st-1)>>3) + 1u) * 1024u;
      const uint32_t* cp = cnt + ((st-1)&7)*16;
      int guard = 0;
      for (;;) {
        uint32_t v = __hip_atomic_load(cp, __ATOMIC_RELAXED, __HIP_MEMORY_SCOPE_AGENT);
        if (v >= tgt) break;
        if (++guard > gmax) { gmax = 0; break; }  // fail fast+loud (NaN)
        if (guard > 8) __builtin_amdgcn_s_sleep(1);
      }
      // acquire: invalidate stale L1/L2 copies, then read state plainly
      __builtin_amdgcn_fence(__ATOMIC_ACQUIRE, "agent");
      const uint4* hrd = (const uint4*)((const char*)(hstate + ((st-1)&1)*4096) + (size_t)t*32);
      uint4 va = hrd[0];
      uint4 vb = hrd[1];
      uint4* hsd = (uint4*)Hs[cur];
      hsd[t*2  ] = va;
      hsd[t*2+1] = vb;
    }
    float4 zc = znx, gc = gnx;
    asm volatile("s_waitcnt lgkmcnt(0)\ns_barrier" ::: "memory");   // B1: staged
    f32x4 acc = {0.f,0.f,0.f,0.f};
    if (st > 0) {
      f32x4 acc1 = {0.f,0.f,0.f,0.f};
      const uint4 z4 = make_uint4(0u,0u,0u,0u);
      #pragma unroll
      for (int kt=0;kt<16;kt+=2) {
        Frag b0, b1;
        b0.u = (c<4) ? *(const uint4*)&Hs[cur][c*1024 + kh*512 + (kt  )*32 + quad*8] : z4;
        b1.u = (c<4) ? *(const uint4*)&Hs[cur][c*1024 + kh*512 + (kt+1)*32 + quad*8] : z4;
        acc  = __builtin_amdgcn_mfma_f32_16x16x32_bf16(a[kt  ].b, b0.b, acc,  0,0,0);
        acc1 = __builtin_amdgcn_mfma_f32_16x16x32_bf16(a[kt+1].b, b1.b, acc1, 0,0,0);
      }
      #pragma unroll
      for (int r=0;r<4;r++) acc[r] += acc1[r];
    }
    if (kh == 1) {
      #pragma unroll
      for (int r=0;r<4;r++) redbuf[mt][lane][r] = acc[r];
    }
    asm volatile("s_waitcnt lgkmcnt(0)\ns_barrier" ::: "memory");   // B2: redbuf
    if (epi) {
      ushort hb[4];
      float zr[4] = {zc.x, zc.y, zc.z, zc.w};
      float gr[4] = {gc.x, gc.y, gc.z, gc.w};
      #pragma unroll
      for (int r=0;r<4;r++) {
        float g = acc[r] + redbuf[mt][lane][r] + bgv[r];
        g = 1.f/(1.f+__expf(-g));
        float hp = (st>0) ? bf2f(Hs[cur][c*1024 + n0w + r]) : 0.f;
        hb[r] = f2bf(zr[r]*g + gr[r]*hp);
      }
      uint32_t p0 = (uint32_t)hb[0] | ((uint32_t)hb[1]<<16);
      uint32_t p1 = (uint32_t)hb[2] | ((uint32_t)hb[3]<<16);
      uint64_t pk = ((uint64_t)p1<<32) | (uint64_t)p0;
      uint64_t* hwd = (uint64_t*)(hstate + (st&1)*4096);
      __hip_atomic_store(hwd + qi, pk, __ATOMIC_RELAXED, __HIP_MEMORY_SCOPE_AGENT);
      uint64_t* sq = (uint64_t*)(hseq + ((size_t)c*SS + st)*DD + n0w);
      __hip_atomic_store(sq, pk, __ATOMIC_RELAXED, __HIP_MEMORY_SCOPE_AGENT);
    }
    // one release add per epi wave: orders this wave's stores before the flag
    if (kh == 0 && lane == 0)
      __hip_atomic_fetch_add(cnt + (st&7)*16, 16u,
                             __ATOMIC_RELEASE, __HIP_MEMORY_SCOPE_AGENT);
    // prefetch next step's z/gamma AFTER the add (keeps L3 latency out of
    // the release drain); consumed at st+1's epilogue
    if (epi && (st+1 < SS)) {
      znx = *(const float4*)(z32  + ((size_t)c*SS + (st+1))*DD + n0w);
      gnx = *(const float4*)(gm32 + ((size_t)c*SS + (st+1))*DD + n0w);
    }
    // no loop-end barrier: Hs double-buffered; a wave racing into st+1 just
    // polls cnt until producers (waves 0,1) finish their adds
  }
}

// --------------------------------------------------------------- launch -----
extern "C" void kernel_launch(void* const* d_in, const int* in_sizes, int n_in,
                              void* d_out, int out_size, void* d_ws, size_t ws_size,
                              hipStream_t stream)
{
  const float* x   = (const float*)d_in[0];
  const float* n1w = (const float*)d_in[1];
  const float* Wq  = (const float*)d_in[2];
  const float* bq  = (const float*)d_in[3];
  const float* Wk  = (const float*)d_in[4];
  const float* bk  = (const float*)d_in[5];
  const float* Wv  = (const float*)d_in[6];
  const float* bv  = (const float*)d_in[7];
  const float* Wz  = (const float*)d_in[8];
  const float* bz  = (const float*)d_in[9];
  const float* Wg_ = (const float*)d_in[10];
  const float* bg  = (const float*)d_in[11];
  const float* gdw = (const float*)d_in[12];
  const float* gdb = (const float*)d_in[13];
  const float* guw = (const float*)d_in[14];
  const float* gub = (const float*)d_in[15];
  const float* Wo  = (const float*)d_in[16];
  const float* bo  = (const float*)d_in[17];
  const float* n2w = (const float*)d_in[18];
  const float* f1w = (const float*)d_in[19];
  const float* f1b = (const float*)d_in[20];
  const float* f2w = (const float*)d_in[21];
  const float* f2b = (const float*)d_in[22];

  char* ws = (char*)d_ws;
  const size_t MB = (size_t)1<<20;
  ushort* Wqb  = (ushort*)(ws +  0*MB);
  ushort* Wkb  = (ushort*)(ws +  2*MB);
  ushort* Wvb  = (ushort*)(ws +  4*MB);
  ushort* Wzb  = (ushort*)(ws +  6*MB);
  ushort* Wob  = (ushort*)(ws +  8*MB);
  ushort* Wgb  = (ushort*)(ws + 10*MB);
  ushort* gdwb = (ushort*)(ws + 12*MB);
  ushort* guwb = (ushort*)(ws + 12*MB + (512<<10));
  ushort* f1wb = (ushort*)(ws + 13*MB);
  ushort* f2wb = (ushort*)(ws + 21*MB);
  ushort* xn   = (ushort*)(ws + 29*MB);
  ushort* qb   = (ushort*)(ws + 37*MB);
  ushort* kb   = (ushort*)(ws + 45*MB);
  ushort* vb   = (ushort*)(ws + 53*MB);
  ushort* zb16 = (ushort*)(ws + 61*MB);
  ushort* ff1  = (ushort*)(ws + 37*MB);   // aliases qb..zb16 (dead by then)
  ushort* t1   = (ushort*)(ws + 69*MB);
  ushort* hseq = (ushort*)(ws + 70*MB);
  ushort* aob  = (ushort*)(ws + 78*MB);
  float*  zb32 = (float*) (ws + 86*MB);
  float*  yf   = (float*) (ws + 86*MB);   // aliases zb32 (dead after scan)
  float*  gm32 = (float*) (ws +102*MB);
  ushort* hst  = (ushort*)(ws +118*MB);   // 2 x 4096 bf16 state (16 KB)
  uint32_t* cnt = (uint32_t*)(ws +118*MB + (64<<10));  // 8 x 64B counters
  ushort* yn = xn;

  // 0. cast weights fp32 -> bf16
  cast_k<<<1024, 256, 0, stream>>>(Wq,  Wqb, 1048576);
  cast_k<<<1024, 256, 0, stream>>>(Wk,  Wkb, 1048576);
  cast_k<<<1024, 256, 0, stream>>>(Wv,  Wvb, 1048576);
  cast_k<<<1024, 256, 0, stream>>>(Wz,  Wzb, 1048576);
  cast_k<<<1024, 256, 0, stream>>>(Wo,  Wob, 1048576);
  cast_k<<<1024, 256, 0, stream>>>(Wg_, Wgb, 1048576);
  cast_k<<< 128, 256, 0, stream>>>(gdw, gdwb, 131072);
  cast_k<<< 128, 256, 0, stream>>>(guw, guwb, 131072);
  cast_k<<<4096, 256, 0, stream>>>(f1w, f1wb, 4194304);
  cast_k<<<4096, 256, 0, stream>>>(f2w, f2wb, 4194304);
  // 1. rmsnorm(x)
  rmsnorm_k<<<4096, 256, 0, stream>>>(x, n1w, xn);
  // 2. Q/K/V/Z projections
  gemm_bt<ACT_NONE,EPI_B16 ><<<dim3(32,8), 256, 0, stream>>>(xn, Wqb, bq, 1024, 1024, qb,  nullptr, nullptr, nullptr, nullptr);
  gemm_bt<ACT_NONE,EPI_B16 ><<<dim3(32,8), 256, 0, stream>>>(xn, Wkb, bk, 1024, 1024, kb,  nullptr, nullptr, nullptr, nullptr);
  gemm_bt<ACT_NONE,EPI_B16 ><<<dim3(32,8), 256, 0, stream>>>(xn, Wvb, bv, 1024, 1024, vb,  nullptr, nullptr, nullptr, nullptr);
  gemm_bt<ACT_NONE,EPI_DUAL><<<dim3(32,8), 256, 0, stream>>>(xn, Wzb, bz, 1024, 1024, zb16, zb32,   nullptr, nullptr, nullptr);
  // 3. gamma
  gemm_bt<ACT_RELU,EPI_B16><<<dim3(32,1), 256, 0, stream>>>(zb16, gdwb, gdb, 128, 1024, t1, nullptr, nullptr, nullptr, nullptr);
  gemm_bt<ACT_SIG ,EPI_F32><<<dim3(32,8), 256, 0, stream>>>(t1, guwb, gub, 1024, 128, nullptr, gm32, nullptr, nullptr, nullptr);
  // 4. attention
  attn_k<<<dim3(16,64), 256, 0, stream>>>(qb, kb, vb, aob);
  // 5. recurrence (counters zeroed; no sentinel ring needed)
  (void)hipMemsetAsync(cnt, 0, 512, stream);
  scan_k<<<dim3(NBS), 256, 0, stream>>>(Wgb, bg, zb32, gm32, hseq, hst, cnt);
  // 6. y = x + ao@Wo.T+bo + hseq
  gemm_bt<ACT_NONE,EPI_Y><<<dim3(32,8), 256, 0, stream>>>(aob, Wob, bo, 1024, 1024, nullptr, yf, x, hseq, nullptr);
  // 7. FFN + out
  rmsnorm_k<<<4096, 256, 0, stream>>>(yf, n2w, yn);
  gemm_bt<ACT_GELU,EPI_B16><<<dim3(32,32), 256, 0, stream>>>(yn, f1wb, f1b, 4096, 1024, ff1, nullptr, nullptr, nullptr, nullptr);
  gemm_bt<ACT_NONE,EPI_OUT><<<dim3(32,8), 256, 0, stream>>>(ff1, f2wb, f2b, 1024, 4096, nullptr, (float*)d_out, nullptr, nullptr, yf);
}

// Round 8
// 4439.943 us; speedup vs baseline: 2.1243x; 2.1243x over previous
//
#include <hip/hip_runtime.h>
#include <stdint.h>

#define DD 1024   // D
#define SS 1024   // S
#define NBS 32    // scan blocks (co-resident: first 32 blocks of fused grid)

typedef __attribute__((ext_vector_type(8))) __bf16 bf16x8;
typedef __attribute__((ext_vector_type(4))) float f32x4;

union Frag { uint4 u; bf16x8 b; };

__device__ __forceinline__ float bf2f(ushort u){ union{uint32_t i; float f;} c; c.i = ((uint32_t)u)<<16; return c.f; }
__device__ __forceinline__ float bflo(uint32_t p){ union{uint32_t i; float f;} c; c.i = p<<16; return c.f; }
__device__ __forceinline__ float bfhi(uint32_t p){ union{uint32_t i; float f;} c; c.i = p & 0xffff0000u; return c.f; }
__device__ __forceinline__ ushort f2bf(float f){
  union{float f; uint32_t u;} c; c.f = f;
  uint32_t u = c.u;
  return (ushort)((u + 0x7fffu + ((u>>16)&1u)) >> 16);   // RNE
}

// ------------------------------------------------------------------- cast ---
__global__ __launch_bounds__(256) void cast_k(const float* __restrict__ s,
    ushort* __restrict__ d, int n)
{
  int i = (blockIdx.x*256 + threadIdx.x)*4;
  if (i >= n) return;
  float4 v = *(const float4*)(s+i);
  ushort4 o; o.x=f2bf(v.x); o.y=f2bf(v.y); o.z=f2bf(v.z); o.w=f2bf(v.w);
  *(ushort4*)(d+i) = o;
}

// ---------------------------------------------------------------- rmsnorm ---
__global__ __launch_bounds__(256) void rmsnorm_k(const float* __restrict__ X,
    const float* __restrict__ w, ushort* __restrict__ out)
{
  const int row = blockIdx.x, t = threadIdx.x;
  const float* x = X + (size_t)row*DD;
  float xs[4]; float s = 0.f;
  #pragma unroll
  for (int i=0;i<4;i++){ float v = x[t + i*256]; xs[i]=v; s += v*v; }
  #pragma unroll
  for (int off=32; off>0; off>>=1) s += __shfl_xor(s, off, 64);
  __shared__ float sred[4];
  if ((t&63)==0) sred[t>>6] = s;
  __syncthreads();
  s = sred[0]+sred[1]+sred[2]+sred[3];
  float inv = 1.f/(sqrtf(s)*0.03125f + 1e-6f);   // /sqrt(1024), + eps
  #pragma unroll
  for (int i=0;i<4;i++){
    int c2 = t + i*256;
    out[(size_t)row*DD + c2] = f2bf(xs[i]*inv*w[c2]);
  }
}

// ---------------------------------------------------------- MFMA GEMM (BT) --
enum { ACT_NONE=0, ACT_RELU=1, ACT_SIG=2, ACT_GELU=3 };
enum { EPI_B16=0, EPI_DUAL=1, EPI_F32=2, EPI_Y=3, EPI_OUT=4 };

template<int ACT, int EPI>
__global__ __launch_bounds__(256) void gemm_bt(
    const ushort* __restrict__ A, const ushort* __restrict__ W,
    const float* __restrict__ bias, int N, int K,
    ushort* __restrict__ Ob, float* __restrict__ Of,
    const float* __restrict__ X32, const ushort* __restrict__ H16,
    const float* __restrict__ Yf)
{
  __shared__ __align__(16) ushort At[128*32];
  __shared__ __align__(16) ushort Wt[128*32];
  const int tid = threadIdx.x;
  const int wave = tid >> 6, lane = tid & 63;
  const int quad = lane >> 4, l16 = lane & 15;
  const int wr = wave >> 1, wc = wave & 1;
  const int m0 = blockIdx.x * 128, n0 = blockIdx.y * 128;

  f32x4 acc[4][4];
  const f32x4 vz = {0.f,0.f,0.f,0.f};
  #pragma unroll
  for (int i=0;i<4;i++)
    #pragma unroll
    for (int j=0;j<4;j++) acc[i][j] = vz;

  const ushort* gA = A + (size_t)(m0 + wave*32 + (lane>>2))*K + (lane&3)*8;
  const ushort* gW = W + (size_t)(n0 + wave*32 + (lane>>2))*K + (lane&3)*8;
  ushort* lA = At + wave*1024 + lane*8;
  ushort* lW = Wt + wave*1024 + lane*8;

  for (int ko = 0; ko < K; ko += 32) {
    uint4 va  = *(const uint4*)(gA + ko);
    uint4 va2 = *(const uint4*)(gA + ko + (size_t)16*K);
    uint4 vw  = *(const uint4*)(gW + ko);
    uint4 vw2 = *(const uint4*)(gW + ko + (size_t)16*K);
    __syncthreads();
    *(uint4*)lA          = va;
    *(uint4*)(lA + 512)  = va2;
    *(uint4*)lW          = vw;
    *(uint4*)(lW + 512)  = vw2;
    __syncthreads();
    Frag af[4], bfr[4];
    #pragma unroll
    for (int mi=0;mi<4;mi++)
      af[mi].u = *(const uint4*)&At[(wr*64 + mi*16 + l16)*32 + quad*8];
    #pragma unroll
    for (int ni=0;ni<4;ni++)
      bfr[ni].u = *(const uint4*)&Wt[(wc*64 + ni*16 + l16)*32 + quad*8];
    #pragma unroll
    for (int mi=0;mi<4;mi++)
      #pragma unroll
      for (int ni=0;ni<4;ni++)
        acc[mi][ni] = __builtin_amdgcn_mfma_f32_16x16x32_bf16(af[mi].b, bfr[ni].b, acc[mi][ni], 0,0,0);
  }

  float bia[4];
  #pragma unroll
  for (int ni=0;ni<4;ni++) bia[ni] = bias[n0 + wc*64 + ni*16 + l16];
  #pragma unroll
  for (int mi=0;mi<4;mi++) {
    const int row0 = m0 + wr*64 + mi*16 + quad*4;
    #pragma unroll
    for (int ni=0;ni<4;ni++) {
      const int col = n0 + wc*64 + ni*16 + l16;
      #pragma unroll
      for (int r=0;r<4;r++) {
        float vx = acc[mi][ni][r] + bia[ni];
        if (ACT == ACT_RELU) vx = fmaxf(vx, 0.f);
        else if (ACT == ACT_SIG) {
          vx = 1.f/(1.f+__expf(-vx));
          vx = fminf(fmaxf(vx, 1e-6f), 1.f-1e-6f);
        } else if (ACT == ACT_GELU) {
          float ci = 0.7978845608028654f*(vx + 0.044715f*vx*vx*vx);
          float th = 1.f - 2.f/(1.f + __expf(2.f*ci));
          vx = 0.5f*vx*(1.f+th);
        }
        size_t idx = (size_t)(row0 + r)*N + col;
        if (EPI == EPI_B16)      Ob[idx] = f2bf(vx);
        else if (EPI == EPI_DUAL){ Ob[idx] = f2bf(vx); Of[idx] = vx; }
        else if (EPI == EPI_F32)  Of[idx] = vx;
        else if (EPI == EPI_Y)    Of[idx] = vx + X32[idx] + bf2f(H16[idx]);
        else                      Of[idx] = vx + Yf[idx];
      }
    }
  }
}

// ------------------------------------------------- fused scan+attn+casts ----
// Blocks 0..31: the PROVEN R10 scan (byte-identical protocol: data-is-the-
//   flag depth-4 sentinel ring, relaxed agent atomic qword poll/stores,
//   re-sentinel after poll break, 3 lockstep raw barriers (lgkmcnt-only),
//   z/gamma prefetch-1-ahead, self-disarming guard -> NaN fast-fail).
//   Lesson of R12/R13/R14/R15: every "improvement" to this protocol lost.
//   The lockstep barriers BOUND concurrent atomic bursts into the MALL pipe.
// Blocks 32..1055: attention (no dependence on scan; runs on the 224 idle
//   CUs during the scan's ~3.9ms window -> its ~200us comes for free).
// Blocks 1056..10271: Wo/f1w/f2w weight casts (also scan-independent).
// Correctness: disjoint outputs (hseq/hstate vs aob vs Wob/f1wb/f2wb);
// no inter-role communication; scan blocks are the first 32 scheduled.
__global__ __launch_bounds__(256) void fused_k(
    const ushort* __restrict__ Wgb, const float* __restrict__ bg,
    const float* __restrict__ z32, const float* __restrict__ gm32,
    ushort* __restrict__ hseq, ushort* __restrict__ hstate,
    const ushort* __restrict__ q, const ushort* __restrict__ k,
    const ushort* __restrict__ v, ushort* __restrict__ ao,
    const float* __restrict__ Wo32, ushort* __restrict__ Wob,
    const float* __restrict__ f1w32, ushort* __restrict__ f1wb,
    const float* __restrict__ f2w32, ushort* __restrict__ f2wb)
{
  __shared__ __align__(16) char smem[33024];   // attn: 8K Ks + 8K Vs + 16.6K Ps
  const int bid0 = blockIdx.x;                 // scan: 8K Hs + 2.5K redbuf
  const int t = threadIdx.x;

  if (bid0 < 32) {
    // ---------------- scan (R10 verbatim, smem-overlaid) ----------------
    const int blk = bid0;
    const int wave = t>>6, lane = t&63, quad = lane>>4, c = lane&15;
    const int mt = wave & 1, kh = wave >> 1;
    const int nbase = blk*32 + mt*16;
    const bool epi = (kh == 0) && (c < 4);
    const int n0w = nbase + quad*4;
    Frag a[16];                                   // Wg A-frags, loop-invariant
    {
      const ushort* wrow = Wgb + (size_t)(nbase + c)*DD + kh*512 + quad*8;
      #pragma unroll
      for (int kt=0;kt<16;kt++) a[kt].u = *(const uint4*)(wrow + kt*32);
    }
    float bgv[4];
    #pragma unroll
    for (int r=0;r<4;r++) bgv[r] = bg[nbase + quad*4 + r];
    ushort* Hs = (ushort*)smem;                   // [4096]
    float*  redbuf = (float*)(smem + 8192);       // [2][64][5]
    const int qi = (c*1024 + n0w) >> 2;           // this lane's h slice (qword)
    int gmax = 256;                               // poll budget; 0 after trip

    float4 znx = {0,0,0,0}, gnx = {0,0,0,0};
    if (epi) {
      znx = *(const float4*)(z32  + ((size_t)c*SS + 0)*DD + n0w);
      gnx = *(const float4*)(gm32 + ((size_t)c*SS + 0)*DD + n0w);
    }

    for (int st=0; st<SS; st++) {
      if (st > 0) {
        const uint64_t* hrd = (const uint64_t*)(hstate + ((st+3)&3)*4096);
        uint64_t v0,v1,v2,v3;
        int guard = 0;
        for (;;) {
          v0 = __hip_atomic_load(hrd + t*4 + 0, __ATOMIC_RELAXED, __HIP_MEMORY_SCOPE_AGENT);
          v1 = __hip_atomic_load(hrd + t*4 + 1, __ATOMIC_RELAXED, __HIP_MEMORY_SCOPE_AGENT);
          v2 = __hip_atomic_load(hrd + t*4 + 2, __ATOMIC_RELAXED, __HIP_MEMORY_SCOPE_AGENT);
          v3 = __hip_atomic_load(hrd + t*4 + 3, __ATOMIC_RELAXED, __HIP_MEMORY_SCOPE_AGENT);
          bool ok = ((uint32_t)v0 != 0xFFFFFFFFu) & ((uint32_t)(v0>>32) != 0xFFFFFFFFu)
                  & ((uint32_t)v1 != 0xFFFFFFFFu) & ((uint32_t)(v1>>32) != 0xFFFFFFFFu)
                  & ((uint32_t)v2 != 0xFFFFFFFFu) & ((uint32_t)(v2>>32) != 0xFFFFFFFFu)
                  & ((uint32_t)v3 != 0xFFFFFFFFu) & ((uint32_t)(v3>>32) != 0xFFFFFFFFu);
          if (ok) break;
          if (++guard > gmax) { gmax = 0; break; }  // fail fast+loud (NaN)
          __builtin_amdgcn_s_sleep(1);
        }
        if (epi) {
          uint64_t* rst = (uint64_t*)(hstate + ((st+2)&3)*4096);
          __hip_atomic_store(rst + qi, 0xFFFFFFFFFFFFFFFFull,
                             __ATOMIC_RELAXED, __HIP_MEMORY_SCOPE_AGENT);
        }
        uint64_t* hsd = (uint64_t*)Hs;
        hsd[t*4+0]=v0; hsd[t*4+1]=v1; hsd[t*4+2]=v2; hsd[t*4+3]=v3;
      }
      float4 zc = znx, gc = gnx;
      if (epi && (st+1 < SS)) {
        znx = *(const float4*)(z32  + ((size_t)c*SS + (st+1))*DD + n0w);
        gnx = *(const float4*)(gm32 + ((size_t)c*SS + (st+1))*DD + n0w);
      }
      if (st > 0) {
        asm volatile("s_waitcnt lgkmcnt(0)\ns_barrier" ::: "memory");
      }
      f32x4 acc = {0.f,0.f,0.f,0.f};
      if (st > 0) {
        f32x4 acc1 = {0.f,0.f,0.f,0.f};
        const uint4 z4 = make_uint4(0u,0u,0u,0u);
        #pragma unroll
        for (int kt=0;kt<16;kt+=2) {
          Frag b0, b1;
          b0.u = (c<4) ? *(const uint4*)&Hs[c*1024 + kh*512 + (kt  )*32 + quad*8] : z4;
          b1.u = (c<4) ? *(const uint4*)&Hs[c*1024 + kh*512 + (kt+1)*32 + quad*8] : z4;
          acc  = __builtin_amdgcn_mfma_f32_16x16x32_bf16(a[kt  ].b, b0.b, acc,  0,0,0);
          acc1 = __builtin_amdgcn_mfma_f32_16x16x32_bf16(a[kt+1].b, b1.b, acc1, 0,0,0);
        }
        #pragma unroll
        for (int r=0;r<4;r++) acc[r] += acc1[r];
      }
      if (kh == 1) {
        #pragma unroll
        for (int r=0;r<4;r++) redbuf[(mt*64 + lane)*5 + r] = acc[r];
      }
      asm volatile("s_waitcnt lgkmcnt(0)\ns_barrier" ::: "memory");
      if (epi) {
        ushort hb[4];
        float zr[4] = {zc.x, zc.y, zc.z, zc.w};
        float gr[4] = {gc.x, gc.y, gc.z, gc.w};
        #pragma unroll
        for (int r=0;r<4;r++) {
          float g = acc[r] + redbuf[(mt*64 + lane)*5 + r] + bgv[r];
          g = 1.f/(1.f+__expf(-g));
          float hp = (st>0) ? bf2f(Hs[c*1024 + n0w + r]) : 0.f;
          hb[r] = f2bf(zr[r]*g + gr[r]*hp);
        }
        uint32_t p0 = (uint32_t)hb[0] | ((uint32_t)hb[1]<<16);
        uint32_t p1 = (uint32_t)hb[2] | ((uint32_t)hb[3]<<16);
        uint64_t pk = ((uint64_t)p1<<32) | (uint64_t)p0;
        uint64_t* hwd = (uint64_t*)(hstate + (st&3)*4096);
        __hip_atomic_store(hwd + qi, pk, __ATOMIC_RELAXED, __HIP_MEMORY_SCOPE_AGENT);
        uint2* sq = (uint2*)(hseq + ((size_t)c*SS + st)*DD + n0w);
        *sq = make_uint2(p0, p1);          // cached store: stays in L2
      }
      asm volatile("s_waitcnt lgkmcnt(0)\ns_barrier" ::: "memory");  // lockstep
    }
    return;
  }

  if (bid0 < 1056) {
    // ------------------------- attention (verbatim) ----------------------
    const int abid = bid0 - 32;
    const int qt = abid & 15, bh = abid >> 4;
    const int b = bh >> 4, h = bh & 15;
    const int r = t >> 2, seg = t & 3;
    ushort* Ks = (ushort*)smem;                  // [64*64]
    ushort* Vs = (ushort*)(smem + 8192);         // [64*64]
    float*  Ps = (float*)(smem + 16384);         // [64*65]
    const ushort* qrow = q + ((size_t)(b*SS + qt*64 + r))*DD + h*64;
    float qr[64];
    #pragma unroll
    for (int i=0;i<64;i+=8){
      uint4 u = *(const uint4*)(qrow + i);
      qr[i+0]=bflo(u.x); qr[i+1]=bfhi(u.x); qr[i+2]=bflo(u.y); qr[i+3]=bfhi(u.y);
      qr[i+4]=bflo(u.z); qr[i+5]=bfhi(u.z); qr[i+6]=bflo(u.w); qr[i+7]=bfhi(u.w);
    }
    float o[16];
    #pragma unroll
    for (int i=0;i<16;i++) o[i]=0.f;
    float mrun = -1e30f, lrun = 0.f;
    const int jrow = t >> 3, jch = t & 7;
    for (int kt=0; kt<16; kt++) {
      __syncthreads();
      const ushort* kg = k + ((size_t)(b*SS + kt*64))*DD + h*64;
      const ushort* vg = v + ((size_t)(b*SS + kt*64))*DD + h*64;
      #pragma unroll
      for (int part=0; part<2; part++){
        int j = jrow + part*32;
        *(uint4*)&Ks[j*64 + jch*8] = *(const uint4*)(kg + (size_t)j*DD + jch*8);
        *(uint4*)&Vs[j*64 + jch*8] = *(const uint4*)(vg + (size_t)j*DD + jch*8);
      }
      __syncthreads();
      float sc[16];
      #pragma unroll
      for (int jj=0;jj<16;jj++){
        int j = seg*16 + jj;
        float s_ = 0.f;
        #pragma unroll
        for (int i=0;i<64;i+=8){
          uint4 u = *(const uint4*)&Ks[j*64+i];
          s_ = fmaf(qr[i+0], bflo(u.x), s_); s_ = fmaf(qr[i+1], bfhi(u.x), s_);
          s_ = fmaf(qr[i+2], bflo(u.y), s_); s_ = fmaf(qr[i+3], bfhi(u.y), s_);
          s_ = fmaf(qr[i+4], bflo(u.z), s_); s_ = fmaf(qr[i+5], bfhi(u.z), s_);
          s_ = fmaf(qr[i+6], bflo(u.w), s_); s_ = fmaf(qr[i+7], bfhi(u.w), s_);
        }
        sc[jj] = s_ * 0.125f;
      }
      float mx = sc[0];
      #pragma unroll
      for (int jj=1;jj<16;jj++) mx = fmaxf(mx, sc[jj]);
      mx = fmaxf(mx, __shfl_xor(mx, 1, 64));
      mx = fmaxf(mx, __shfl_xor(mx, 2, 64));
      float mnew = fmaxf(mrun, mx);
      float psum = 0.f;
      #pragma unroll
      for (int jj=0;jj<16;jj++){
        float p = __expf(sc[jj]-mnew);
        Ps[r*65 + seg*16 + jj] = p;
        psum += p;
      }
      psum += __shfl_xor(psum, 1, 64);
      psum += __shfl_xor(psum, 2, 64);
      float alpha = __expf(mrun - mnew);
      lrun = lrun*alpha + psum;
      mrun = mnew;
      #pragma unroll
      for (int i=0;i<16;i++) o[i] *= alpha;
      __syncthreads();
      #pragma unroll 4
      for (int j=0;j<64;j++){
        float pj = Ps[r*65 + j];
        uint4 u0 = *(const uint4*)&Vs[j*64 + seg*16];
        uint4 u1 = *(const uint4*)&Vs[j*64 + seg*16 + 8];
        o[ 0]=fmaf(pj,bflo(u0.x),o[ 0]); o[ 1]=fmaf(pj,bfhi(u0.x),o[ 1]);
        o[ 2]=fmaf(pj,bflo(u0.y),o[ 2]); o[ 3]=fmaf(pj,bfhi(u0.y),o[ 3]);
        o[ 4]=fmaf(pj,bflo(u0.z),o[ 4]); o[ 5]=fmaf(pj,bfhi(u0.z),o[ 5]);
        o[ 6]=fmaf(pj,bflo(u0.w),o[ 6]); o[ 7]=fmaf(pj,bfhi(u0.w),o[ 7]);
        o[ 8]=fmaf(pj,bflo(u1.x),o[ 8]); o[ 9]=fmaf(pj,bfhi(u1.x),o[ 9]);
        o[10]=fmaf(pj,bflo(u1.y),o[10]); o[11]=fmaf(pj,bfhi(u1.y),o[11]);
        o[12]=fmaf(pj,bflo(u1.z),o[12]); o[13]=fmaf(pj,bfhi(u1.z),o[13]);
        o[14]=fmaf(pj,bflo(u1.w),o[14]); o[15]=fmaf(pj,bfhi(u1.w),o[15]);
      }
    }
    float invl = 1.f/lrun;
    ushort* orow = ao + ((size_t)(b*SS + qt*64 + r))*DD + h*64 + seg*16;
    #pragma unroll
    for (int i=0;i<16;i++) orow[i] = f2bf(o[i]*invl);
    return;
  }

  // ------------------------------ casts ----------------------------------
  {
    int cbid = bid0 - 1056;
    const float* src; ushort* dst; int n;
    if (cbid < 1024)      { src = Wo32;  dst = Wob;  n = 1048576; }
    else if (cbid < 5120) { src = f1w32; dst = f1wb; n = 4194304; cbid -= 1024; }
    else                  { src = f2w32; dst = f2wb; n = 4194304; cbid -= 5120; }
    int i = (cbid*256 + t)*4;
    if (i >= n) return;
    float4 vv = *(const float4*)(src+i);
    ushort4 oo; oo.x=f2bf(vv.x); oo.y=f2bf(vv.y); oo.z=f2bf(vv.z); oo.w=f2bf(vv.w);
    *(ushort4*)(dst+i) = oo;
  }
}

// --------------------------------------------------------------- launch -----
extern "C" void kernel_launch(void* const* d_in, const int* in_sizes, int n_in,
                              void* d_out, int out_size, void* d_ws, size_t ws_size,
                              hipStream_t stream)
{
  const float* x   = (const float*)d_in[0];
  const float* n1w = (const float*)d_in[1];
  const float* Wq  = (const float*)d_in[2];
  const float* bq  = (const float*)d_in[3];
  const float* Wk  = (const float*)d_in[4];
  const float* bk  = (const float*)d_in[5];
  const float* Wv  = (const float*)d_in[6];
  const float* bv  = (const float*)d_in[7];
  const float* Wz  = (const float*)d_in[8];
  const float* bz  = (const float*)d_in[9];
  const float* Wg_ = (const float*)d_in[10];
  const float* bg  = (const float*)d_in[11];
  const float* gdw = (const float*)d_in[12];
  const float* gdb = (const float*)d_in[13];
  const float* guw = (const float*)d_in[14];
  const float* gub = (const float*)d_in[15];
  const float* Wo  = (const float*)d_in[16];
  const float* bo  = (const float*)d_in[17];
  const float* n2w = (const float*)d_in[18];
  const float* f1w = (const float*)d_in[19];
  const float* f1b = (const float*)d_in[20];
  const float* f2w = (const float*)d_in[21];
  const float* f2b = (const float*)d_in[22];

  char* ws = (char*)d_ws;
  const size_t MB = (size_t)1<<20;
  ushort* Wqb  = (ushort*)(ws +  0*MB);
  ushort* Wkb  = (ushort*)(ws +  2*MB);
  ushort* Wvb  = (ushort*)(ws +  4*MB);
  ushort* Wzb  = (ushort*)(ws +  6*MB);
  ushort* Wob  = (ushort*)(ws +  8*MB);
  ushort* Wgb  = (ushort*)(ws + 10*MB);
  ushort* gdwb = (ushort*)(ws + 12*MB);
  ushort* guwb = (ushort*)(ws + 12*MB + (512<<10));
  ushort* f1wb = (ushort*)(ws + 13*MB);
  ushort* f2wb = (ushort*)(ws + 21*MB);
  ushort* xn   = (ushort*)(ws + 29*MB);
  ushort* qb   = (ushort*)(ws + 37*MB);
  ushort* kb   = (ushort*)(ws + 45*MB);
  ushort* vb   = (ushort*)(ws + 53*MB);
  ushort* zb16 = (ushort*)(ws + 61*MB);
  ushort* ff1  = (ushort*)(ws + 37*MB);   // aliases qb..zb16 (dead by then)
  ushort* t1   = (ushort*)(ws + 69*MB);
  ushort* hseq = (ushort*)(ws + 70*MB);
  ushort* aob  = (ushort*)(ws + 78*MB);
  float*  zb32 = (float*) (ws + 86*MB);
  float*  yf   = (float*) (ws + 86*MB);   // aliases zb32 (dead after scan)
  float*  gm32 = (float*) (ws +102*MB);
  ushort* hst  = (ushort*)(ws +118*MB);   // 4 x 4096 bf16 ring (32 KB)
  ushort* yn = xn;

  // 0. cast early weights fp32 -> bf16 (Wo/f1w/f2w casts folded into fused_k)
  cast_k<<<1024, 256, 0, stream>>>(Wq,  Wqb, 1048576);
  cast_k<<<1024, 256, 0, stream>>>(Wk,  Wkb, 1048576);
  cast_k<<<1024, 256, 0, stream>>>(Wv,  Wvb, 1048576);
  cast_k<<<1024, 256, 0, stream>>>(Wz,  Wzb, 1048576);
  cast_k<<<1024, 256, 0, stream>>>(Wg_, Wgb, 1048576);
  cast_k<<< 128, 256, 0, stream>>>(gdw, gdwb, 131072);
  cast_k<<< 128, 256, 0, stream>>>(guw, guwb, 131072);
  // 1. rmsnorm(x)
  rmsnorm_k<<<4096, 256, 0, stream>>>(x, n1w, xn);
  // 2. Q/K/V/Z projections
  gemm_bt<ACT_NONE,EPI_B16 ><<<dim3(32,8), 256, 0, stream>>>(xn, Wqb, bq, 1024, 1024, qb,  nullptr, nullptr, nullptr, nullptr);
  gemm_bt<ACT_NONE,EPI_B16 ><<<dim3(32,8), 256, 0, stream>>>(xn, Wkb, bk, 1024, 1024, kb,  nullptr, nullptr, nullptr, nullptr);
  gemm_bt<ACT_NONE,EPI_B16 ><<<dim3(32,8), 256, 0, stream>>>(xn, Wvb, bv, 1024, 1024, vb,  nullptr, nullptr, nullptr, nullptr);
  gemm_bt<ACT_NONE,EPI_DUAL><<<dim3(32,8), 256, 0, stream>>>(xn, Wzb, bz, 1024, 1024, zb16, zb32,   nullptr, nullptr, nullptr);
  // 3. gamma
  gemm_bt<ACT_RELU,EPI_B16><<<dim3(32,1), 256, 0, stream>>>(zb16, gdwb, gdb, 128, 1024, t1, nullptr, nullptr, nullptr, nullptr);
  gemm_bt<ACT_SIG ,EPI_F32><<<dim3(32,8), 256, 0, stream>>>(t1, guwb, gub, 1024, 128, nullptr, gm32, nullptr, nullptr, nullptr);
  // 4+5. fused: scan (blocks 0-31) || attention (32-1055) || casts (1056+)
  (void)hipMemsetAsync(hst, 0xFF, 32768, stream);
  fused_k<<<dim3(10272), 256, 0, stream>>>(Wgb, bg, zb32, gm32, hseq, hst,
                                           qb, kb, vb, aob,
                                           Wo, Wob, f1w, f1wb, f2w, f2wb);
  // 6. y = x + ao@Wo.T+bo + hseq
  gemm_bt<ACT_NONE,EPI_Y><<<dim3(32,8), 256, 0, stream>>>(aob, Wob, bo, 1024, 1024, nullptr, yf, x, hseq, nullptr);
  // 7. FFN + out
  rmsnorm_k<<<4096, 256, 0, stream>>>(yf, n2w, yn);
  gemm_bt<ACT_GELU,EPI_B16><<<dim3(32,32), 256, 0, stream>>>(yn, f1wb, f1b, 4096, 1024, ff1, nullptr, nullptr, nullptr, nullptr);
  gemm_bt<ACT_NONE,EPI_OUT><<<dim3(32,8), 256, 0, stream>>>(ff1, f2wb, f2b, 1024, 4096, nullptr, (float*)d_out, nullptr, nullptr, yf);
}

// Round 9
// 4365.123 us; speedup vs baseline: 2.1607x; 1.0171x over previous
//
#include <hip/hip_runtime.h>
#include <stdint.h>

#define DD 1024   // D
#define SS 1024   // S

typedef __attribute__((ext_vector_type(8))) __bf16 bf16x8;
typedef __attribute__((ext_vector_type(4))) float f32x4;

union Frag { uint4 u; bf16x8 b; };

__device__ __forceinline__ float bf2f(ushort u){ union{uint32_t i; float f;} c; c.i = ((uint32_t)u)<<16; return c.f; }
__device__ __forceinline__ float bflo(uint32_t p){ union{uint32_t i; float f;} c; c.i = p<<16; return c.f; }
__device__ __forceinline__ float bfhi(uint32_t p){ union{uint32_t i; float f;} c; c.i = p & 0xffff0000u; return c.f; }
__device__ __forceinline__ ushort f2bf(float f){
  union{float f; uint32_t u;} c; c.f = f;
  uint32_t u = c.u;
  return (ushort)((u + 0x7fffu + ((u>>16)&1u)) >> 16);   // RNE
}

// ---------------------------------------------- fused casts + rmsnorm1 ------
// blocks 0..5375: cast 7 weight arrays fp32->bf16 (Wq,Wk,Wv,Wz,Wg,gdw,guw)
// blocks 5376..9471: rmsnorm(x) -> xn   (independent of the casts)
__global__ __launch_bounds__(256) void prep_k(
    const float* __restrict__ Wq,  ushort* __restrict__ Wqb,
    const float* __restrict__ Wk,  ushort* __restrict__ Wkb,
    const float* __restrict__ Wv,  ushort* __restrict__ Wvb,
    const float* __restrict__ Wz,  ushort* __restrict__ Wzb,
    const float* __restrict__ Wg,  ushort* __restrict__ Wgb,
    const float* __restrict__ gdw, ushort* __restrict__ gdwb,
    const float* __restrict__ guw, ushort* __restrict__ guwb,
    const float* __restrict__ X,   const float* __restrict__ n1w,
    ushort* __restrict__ xn)
{
  const int bid = blockIdx.x, t = threadIdx.x;
  if (bid < 5376) {
    int cbid = bid;
    const float* src; ushort* dst; int n;
    if (cbid < 1024)      { src = Wq;  dst = Wqb;  n = 1048576; }
    else if (cbid < 2048) { src = Wk;  dst = Wkb;  n = 1048576; cbid -= 1024; }
    else if (cbid < 3072) { src = Wv;  dst = Wvb;  n = 1048576; cbid -= 2048; }
    else if (cbid < 4096) { src = Wz;  dst = Wzb;  n = 1048576; cbid -= 3072; }
    else if (cbid < 5120) { src = Wg;  dst = Wgb;  n = 1048576; cbid -= 4096; }
    else if (cbid < 5248) { src = gdw; dst = gdwb; n = 131072;  cbid -= 5120; }
    else                  { src = guw; dst = guwb; n = 131072;  cbid -= 5248; }
    int i = (cbid*256 + t)*4;
    if (i >= n) return;
    float4 v = *(const float4*)(src+i);
    ushort4 o; o.x=f2bf(v.x); o.y=f2bf(v.y); o.z=f2bf(v.z); o.w=f2bf(v.w);
    *(ushort4*)(dst+i) = o;
    return;
  }
  // rmsnorm
  const int row = bid - 5376;
  const float* x = X + (size_t)row*DD;
  float xs[4]; float s = 0.f;
  #pragma unroll
  for (int i=0;i<4;i++){ float v = x[t + i*256]; xs[i]=v; s += v*v; }
  #pragma unroll
  for (int off=32; off>0; off>>=1) s += __shfl_xor(s, off, 64);
  __shared__ float sred[4];
  if ((t&63)==0) sred[t>>6] = s;
  __syncthreads();
  s = sred[0]+sred[1]+sred[2]+sred[3];
  float inv = 1.f/(sqrtf(s)*0.03125f + 1e-6f);   // /sqrt(1024), + eps
  #pragma unroll
  for (int i=0;i<4;i++){
    int c2 = t + i*256;
    xn[(size_t)row*DD + c2] = f2bf(xs[i]*inv*n1w[c2]);
  }
}

// ---------------------------------------------------------------- rmsnorm ---
__global__ __launch_bounds__(256) void rmsnorm_k(const float* __restrict__ X,
    const float* __restrict__ w, ushort* __restrict__ out)
{
  const int row = blockIdx.x, t = threadIdx.x;
  const float* x = X + (size_t)row*DD;
  float xs[4]; float s = 0.f;
  #pragma unroll
  for (int i=0;i<4;i++){ float v = x[t + i*256]; xs[i]=v; s += v*v; }
  #pragma unroll
  for (int off=32; off>0; off>>=1) s += __shfl_xor(s, off, 64);
  __shared__ float sred[4];
  if ((t&63)==0) sred[t>>6] = s;
  __syncthreads();
  s = sred[0]+sred[1]+sred[2]+sred[3];
  float inv = 1.f/(sqrtf(s)*0.03125f + 1e-6f);   // /sqrt(1024), + eps
  #pragma unroll
  for (int i=0;i<4;i++){
    int c2 = t + i*256;
    out[(size_t)row*DD + c2] = f2bf(xs[i]*inv*w[c2]);
  }
}

// ---------------------------------------------------------- MFMA GEMM (BT) --
enum { ACT_NONE=0, ACT_RELU=1, ACT_SIG=2, ACT_GELU=3 };
enum { EPI_B16=0, EPI_DUAL=1, EPI_F32=2, EPI_Y=3, EPI_OUT=4 };

template<int ACT, int EPI>
__global__ __launch_bounds__(256) void gemm_bt(
    const ushort* __restrict__ A, const ushort* __restrict__ W,
    const float* __restrict__ bias, int N, int K,
    ushort* __restrict__ Ob, float* __restrict__ Of,
    const float* __restrict__ X32, const ushort* __restrict__ H16,
    const float* __restrict__ Yf)
{
  __shared__ __align__(16) ushort At[128*32];
  __shared__ __align__(16) ushort Wt[128*32];
  const int tid = threadIdx.x;
  const int wave = tid >> 6, lane = tid & 63;
  const int quad = lane >> 4, l16 = lane & 15;
  const int wr = wave >> 1, wc = wave & 1;
  const int m0 = blockIdx.x * 128, n0 = blockIdx.y * 128;

  f32x4 acc[4][4];
  const f32x4 vz = {0.f,0.f,0.f,0.f};
  #pragma unroll
  for (int i=0;i<4;i++)
    #pragma unroll
    for (int j=0;j<4;j++) acc[i][j] = vz;

  const ushort* gA = A + (size_t)(m0 + wave*32 + (lane>>2))*K + (lane&3)*8;
  const ushort* gW = W + (size_t)(n0 + wave*32 + (lane>>2))*K + (lane&3)*8;
  ushort* lA = At + wave*1024 + lane*8;
  ushort* lW = Wt + wave*1024 + lane*8;

  for (int ko = 0; ko < K; ko += 32) {
    uint4 va  = *(const uint4*)(gA + ko);
    uint4 va2 = *(const uint4*)(gA + ko + (size_t)16*K);
    uint4 vw  = *(const uint4*)(gW + ko);
    uint4 vw2 = *(const uint4*)(gW + ko + (size_t)16*K);
    __syncthreads();
    *(uint4*)lA          = va;
    *(uint4*)(lA + 512)  = va2;
    *(uint4*)lW          = vw;
    *(uint4*)(lW + 512)  = vw2;
    __syncthreads();
    Frag af[4], bfr[4];
    #pragma unroll
    for (int mi=0;mi<4;mi++)
      af[mi].u = *(const uint4*)&At[(wr*64 + mi*16 + l16)*32 + quad*8];
    #pragma unroll
    for (int ni=0;ni<4;ni++)
      bfr[ni].u = *(const uint4*)&Wt[(wc*64 + ni*16 + l16)*32 + quad*8];
    #pragma unroll
    for (int mi=0;mi<4;mi++)
      #pragma unroll
      for (int ni=0;ni<4;ni++)
        acc[mi][ni] = __builtin_amdgcn_mfma_f32_16x16x32_bf16(af[mi].b, bfr[ni].b, acc[mi][ni], 0,0,0);
  }

  float bia[4];
  #pragma unroll
  for (int ni=0;ni<4;ni++) bia[ni] = bias[n0 + wc*64 + ni*16 + l16];
  #pragma unroll
  for (int mi=0;mi<4;mi++) {
    const int row0 = m0 + wr*64 + mi*16 + quad*4;
    #pragma unroll
    for (int ni=0;ni<4;ni++) {
      const int col = n0 + wc*64 + ni*16 + l16;
      #pragma unroll
      for (int r=0;r<4;r++) {
        float vx = acc[mi][ni][r] + bia[ni];
        if (ACT == ACT_RELU) vx = fmaxf(vx, 0.f);
        else if (ACT == ACT_SIG) {
          vx = 1.f/(1.f+__expf(-vx));
          vx = fminf(fmaxf(vx, 1e-6f), 1.f-1e-6f);
        } else if (ACT == ACT_GELU) {
          float ci = 0.7978845608028654f*(vx + 0.044715f*vx*vx*vx);
          float th = 1.f - 2.f/(1.f + __expf(2.f*ci));
          vx = 0.5f*vx*(1.f+th);
        }
        size_t idx = (size_t)(row0 + r)*N + col;
        if (EPI == EPI_B16)      Ob[idx] = f2bf(vx);
        else if (EPI == EPI_DUAL){ Ob[idx] = f2bf(vx); Of[idx] = vx; }
        else if (EPI == EPI_F32)  Of[idx] = vx;
        else if (EPI == EPI_Y)    Of[idx] = vx + X32[idx] + bf2f(H16[idx]);
        else                      Of[idx] = vx + Yf[idx];
      }
    }
  }
}

// --------------------------------------------- fused Q/K/V/Z projections ----
// grid (32, 8, 4): z selects the weight/bias/output set. Identical GEMM body
// (ACT_NONE); z==3 (Z-proj) additionally writes the fp32 copy (EPI_DUAL).
// 1024 blocks in one dispatch -> 4x the CU coverage of the serial version.
__global__ __launch_bounds__(256) void qkvz_k(
    const ushort* __restrict__ A,
    const ushort* __restrict__ Wqb, const ushort* __restrict__ Wkb,
    const ushort* __restrict__ Wvb, const ushort* __restrict__ Wzb,
    const float* __restrict__ bq, const float* __restrict__ bk,
    const float* __restrict__ bv, const float* __restrict__ bz,
    ushort* __restrict__ qb, ushort* __restrict__ kb,
    ushort* __restrict__ vb, ushort* __restrict__ zb16,
    float* __restrict__ zb32)
{
  const int proj = blockIdx.z;
  const ushort* W; const float* bias; ushort* Ob; bool dual = false;
  if (proj == 0)      { W = Wqb; bias = bq; Ob = qb; }
  else if (proj == 1) { W = Wkb; bias = bk; Ob = kb; }
  else if (proj == 2) { W = Wvb; bias = bv; Ob = vb; }
  else                { W = Wzb; bias = bz; Ob = zb16; dual = true; }
  const int N = 1024, K = 1024;

  __shared__ __align__(16) ushort At[128*32];
  __shared__ __align__(16) ushort Wt[128*32];
  const int tid = threadIdx.x;
  const int wave = tid >> 6, lane = tid & 63;
  const int quad = lane >> 4, l16 = lane & 15;
  const int wr = wave >> 1, wc = wave & 1;
  const int m0 = blockIdx.x * 128, n0 = blockIdx.y * 128;

  f32x4 acc[4][4];
  const f32x4 vz = {0.f,0.f,0.f,0.f};
  #pragma unroll
  for (int i=0;i<4;i++)
    #pragma unroll
    for (int j=0;j<4;j++) acc[i][j] = vz;

  const ushort* gA = A + (size_t)(m0 + wave*32 + (lane>>2))*K + (lane&3)*8;
  const ushort* gW = W + (size_t)(n0 + wave*32 + (lane>>2))*K + (lane&3)*8;
  ushort* lA = At + wave*1024 + lane*8;
  ushort* lW = Wt + wave*1024 + lane*8;

  for (int ko = 0; ko < K; ko += 32) {
    uint4 va  = *(const uint4*)(gA + ko);
    uint4 va2 = *(const uint4*)(gA + ko + (size_t)16*K);
    uint4 vw  = *(const uint4*)(gW + ko);
    uint4 vw2 = *(const uint4*)(gW + ko + (size_t)16*K);
    __syncthreads();
    *(uint4*)lA          = va;
    *(uint4*)(lA + 512)  = va2;
    *(uint4*)lW          = vw;
    *(uint4*)(lW + 512)  = vw2;
    __syncthreads();
    Frag af[4], bfr[4];
    #pragma unroll
    for (int mi=0;mi<4;mi++)
      af[mi].u = *(const uint4*)&At[(wr*64 + mi*16 + l16)*32 + quad*8];
    #pragma unroll
    for (int ni=0;ni<4;ni++)
      bfr[ni].u = *(const uint4*)&Wt[(wc*64 + ni*16 + l16)*32 + quad*8];
    #pragma unroll
    for (int mi=0;mi<4;mi++)
      #pragma unroll
      for (int ni=0;ni<4;ni++)
        acc[mi][ni] = __builtin_amdgcn_mfma_f32_16x16x32_bf16(af[mi].b, bfr[ni].b, acc[mi][ni], 0,0,0);
  }

  float bia[4];
  #pragma unroll
  for (int ni=0;ni<4;ni++) bia[ni] = bias[n0 + wc*64 + ni*16 + l16];
  #pragma unroll
  for (int mi=0;mi<4;mi++) {
    const int row0 = m0 + wr*64 + mi*16 + quad*4;
    #pragma unroll
    for (int ni=0;ni<4;ni++) {
      const int col = n0 + wc*64 + ni*16 + l16;
      #pragma unroll
      for (int r=0;r<4;r++) {
        float vx = acc[mi][ni][r] + bia[ni];
        size_t idx = (size_t)(row0 + r)*N + col;
        Ob[idx] = f2bf(vx);
        if (dual) zb32[idx] = vx;
      }
    }
  }
}

// ------------------------------------------------- fused scan+attn+casts ----
// Blocks 0..31: the PROVEN R10 scan (byte-identical protocol). Blocks
// 32..1055: attention. Blocks 1056..10271: Wo/f1w/f2w casts. See R16 notes:
// lockstep barriers bound concurrent atomic bursts; all protocol "upgrades"
// (R12/R13/R14/R15) lost to this structure.
__global__ __launch_bounds__(256) void fused_k(
    const ushort* __restrict__ Wgb, const float* __restrict__ bg,
    const float* __restrict__ z32, const float* __restrict__ gm32,
    ushort* __restrict__ hseq, ushort* __restrict__ hstate,
    const ushort* __restrict__ q, const ushort* __restrict__ k,
    const ushort* __restrict__ v, ushort* __restrict__ ao,
    const float* __restrict__ Wo32, ushort* __restrict__ Wob,
    const float* __restrict__ f1w32, ushort* __restrict__ f1wb,
    const float* __restrict__ f2w32, ushort* __restrict__ f2wb)
{
  __shared__ __align__(16) char smem[33024];   // attn: 8K Ks + 8K Vs + 16.6K Ps
  const int bid0 = blockIdx.x;                 // scan: 8K Hs + 2.5K redbuf
  const int t = threadIdx.x;

  if (bid0 < 32) {
    // ---------------- scan (R10 verbatim, smem-overlaid) ----------------
    const int blk = bid0;
    const int wave = t>>6, lane = t&63, quad = lane>>4, c = lane&15;
    const int mt = wave & 1, kh = wave >> 1;
    const int nbase = blk*32 + mt*16;
    const bool epi = (kh == 0) && (c < 4);
    const int n0w = nbase + quad*4;
    Frag a[16];                                   // Wg A-frags, loop-invariant
    {
      const ushort* wrow = Wgb + (size_t)(nbase + c)*DD + kh*512 + quad*8;
      #pragma unroll
      for (int kt=0;kt<16;kt++) a[kt].u = *(const uint4*)(wrow + kt*32);
    }
    float bgv[4];
    #pragma unroll
    for (int r=0;r<4;r++) bgv[r] = bg[nbase + quad*4 + r];
    ushort* Hs = (ushort*)smem;                   // [4096]
    float*  redbuf = (float*)(smem + 8192);       // [2][64][5]
    const int qi = (c*1024 + n0w) >> 2;           // this lane's h slice (qword)
    int gmax = 256;                               // poll budget; 0 after trip

    float4 znx = {0,0,0,0}, gnx = {0,0,0,0};
    if (epi) {
      znx = *(const float4*)(z32  + ((size_t)c*SS + 0)*DD + n0w);
      gnx = *(const float4*)(gm32 + ((size_t)c*SS + 0)*DD + n0w);
    }

    for (int st=0; st<SS; st++) {
      if (st > 0) {
        const uint64_t* hrd = (const uint64_t*)(hstate + ((st+3)&3)*4096);
        uint64_t v0,v1,v2,v3;
        int guard = 0;
        for (;;) {
          v0 = __hip_atomic_load(hrd + t*4 + 0, __ATOMIC_RELAXED, __HIP_MEMORY_SCOPE_AGENT);
          v1 = __hip_atomic_load(hrd + t*4 + 1, __ATOMIC_RELAXED, __HIP_MEMORY_SCOPE_AGENT);
          v2 = __hip_atomic_load(hrd + t*4 + 2, __ATOMIC_RELAXED, __HIP_MEMORY_SCOPE_AGENT);
          v3 = __hip_atomic_load(hrd + t*4 + 3, __ATOMIC_RELAXED, __HIP_MEMORY_SCOPE_AGENT);
          bool ok = ((uint32_t)v0 != 0xFFFFFFFFu) & ((uint32_t)(v0>>32) != 0xFFFFFFFFu)
                  & ((uint32_t)v1 != 0xFFFFFFFFu) & ((uint32_t)(v1>>32) != 0xFFFFFFFFu)
                  & ((uint32_t)v2 != 0xFFFFFFFFu) & ((uint32_t)(v2>>32) != 0xFFFFFFFFu)
                  & ((uint32_t)v3 != 0xFFFFFFFFu) & ((uint32_t)(v3>>32) != 0xFFFFFFFFu);
          if (ok) break;
          if (++guard > gmax) { gmax = 0; break; }  // fail fast+loud (NaN)
          __builtin_amdgcn_s_sleep(1);
        }
        if (epi) {
          uint64_t* rst = (uint64_t*)(hstate + ((st+2)&3)*4096);
          __hip_atomic_store(rst + qi, 0xFFFFFFFFFFFFFFFFull,
                             __ATOMIC_RELAXED, __HIP_MEMORY_SCOPE_AGENT);
        }
        uint64_t* hsd = (uint64_t*)Hs;
        hsd[t*4+0]=v0; hsd[t*4+1]=v1; hsd[t*4+2]=v2; hsd[t*4+3]=v3;
      }
      float4 zc = znx, gc = gnx;
      if (epi && (st+1 < SS)) {
        znx = *(const float4*)(z32  + ((size_t)c*SS + (st+1))*DD + n0w);
        gnx = *(const float4*)(gm32 + ((size_t)c*SS + (st+1))*DD + n0w);
      }
      if (st > 0) {
        asm volatile("s_waitcnt lgkmcnt(0)\ns_barrier" ::: "memory");
      }
      f32x4 acc = {0.f,0.f,0.f,0.f};
      if (st > 0) {
        f32x4 acc1 = {0.f,0.f,0.f,0.f};
        const uint4 z4 = make_uint4(0u,0u,0u,0u);
        #pragma unroll
        for (int kt=0;kt<16;kt+=2) {
          Frag b0, b1;
          b0.u = (c<4) ? *(const uint4*)&Hs[c*1024 + kh*512 + (kt  )*32 + quad*8] : z4;
          b1.u = (c<4) ? *(const uint4*)&Hs[c*1024 + kh*512 + (kt+1)*32 + quad*8] : z4;
          acc  = __builtin_amdgcn_mfma_f32_16x16x32_bf16(a[kt  ].b, b0.b, acc,  0,0,0);
          acc1 = __builtin_amdgcn_mfma_f32_16x16x32_bf16(a[kt+1].b, b1.b, acc1, 0,0,0);
        }
        #pragma unroll
        for (int r=0;r<4;r++) acc[r] += acc1[r];
      }
      if (kh == 1) {
        #pragma unroll
        for (int r=0;r<4;r++) redbuf[(mt*64 + lane)*5 + r] = acc[r];
      }
      asm volatile("s_waitcnt lgkmcnt(0)\ns_barrier" ::: "memory");
      if (epi) {
        ushort hb[4];
        float zr[4] = {zc.x, zc.y, zc.z, zc.w};
        float gr[4] = {gc.x, gc.y, gc.z, gc.w};
        #pragma unroll
        for (int r=0;r<4;r++) {
          float g = acc[r] + redbuf[(mt*64 + lane)*5 + r] + bgv[r];
          g = 1.f/(1.f+__expf(-g));
          float hp = (st>0) ? bf2f(Hs[c*1024 + n0w + r]) : 0.f;
          hb[r] = f2bf(zr[r]*g + gr[r]*hp);
        }
        uint32_t p0 = (uint32_t)hb[0] | ((uint32_t)hb[1]<<16);
        uint32_t p1 = (uint32_t)hb[2] | ((uint32_t)hb[3]<<16);
        uint64_t pk = ((uint64_t)p1<<32) | (uint64_t)p0;
        uint64_t* hwd = (uint64_t*)(hstate + (st&3)*4096);
        __hip_atomic_store(hwd + qi, pk, __ATOMIC_RELAXED, __HIP_MEMORY_SCOPE_AGENT);
        uint2* sq = (uint2*)(hseq + ((size_t)c*SS + st)*DD + n0w);
        *sq = make_uint2(p0, p1);          // cached store: stays in L2
      }
      asm volatile("s_waitcnt lgkmcnt(0)\ns_barrier" ::: "memory");  // lockstep
    }
    return;
  }

  if (bid0 < 1056) {
    // ------------------------- attention (verbatim) ----------------------
    const int abid = bid0 - 32;
    const int qt = abid & 15, bh = abid >> 4;
    const int b = bh >> 4, h = bh & 15;
    const int r = t >> 2, seg = t & 3;
    ushort* Ks = (ushort*)smem;                  // [64*64]
    ushort* Vs = (ushort*)(smem + 8192);         // [64*64]
    float*  Ps = (float*)(smem + 16384);         // [64*65]
    const ushort* qrow = q + ((size_t)(b*SS + qt*64 + r))*DD + h*64;
    float qr[64];
    #pragma unroll
    for (int i=0;i<64;i+=8){
      uint4 u = *(const uint4*)(qrow + i);
      qr[i+0]=bflo(u.x); qr[i+1]=bfhi(u.x); qr[i+2]=bflo(u.y); qr[i+3]=bfhi(u.y);
      qr[i+4]=bflo(u.z); qr[i+5]=bfhi(u.z); qr[i+6]=bflo(u.w); qr[i+7]=bfhi(u.w);
    }
    float o[16];
    #pragma unroll
    for (int i=0;i<16;i++) o[i]=0.f;
    float mrun = -1e30f, lrun = 0.f;
    const int jrow = t >> 3, jch = t & 7;
    for (int kt=0; kt<16; kt++) {
      __syncthreads();
      const ushort* kg = k + ((size_t)(b*SS + kt*64))*DD + h*64;
      const ushort* vg = v + ((size_t)(b*SS + kt*64))*DD + h*64;
      #pragma unroll
      for (int part=0; part<2; part++){
        int j = jrow + part*32;
        *(uint4*)&Ks[j*64 + jch*8] = *(const uint4*)(kg + (size_t)j*DD + jch*8);
        *(uint4*)&Vs[j*64 + jch*8] = *(const uint4*)(vg + (size_t)j*DD + jch*8);
      }
      __syncthreads();
      float sc[16];
      #pragma unroll
      for (int jj=0;jj<16;jj++){
        int j = seg*16 + jj;
        float s_ = 0.f;
        #pragma unroll
        for (int i=0;i<64;i+=8){
          uint4 u = *(const uint4*)&Ks[j*64+i];
          s_ = fmaf(qr[i+0], bflo(u.x), s_); s_ = fmaf(qr[i+1], bfhi(u.x), s_);
          s_ = fmaf(qr[i+2], bflo(u.y), s_); s_ = fmaf(qr[i+3], bfhi(u.y), s_);
          s_ = fmaf(qr[i+4], bflo(u.z), s_); s_ = fmaf(qr[i+5], bfhi(u.z), s_);
          s_ = fmaf(qr[i+6], bflo(u.w), s_); s_ = fmaf(qr[i+7], bfhi(u.w), s_);
        }
        sc[jj] = s_ * 0.125f;
      }
      float mx = sc[0];
      #pragma unroll
      for (int jj=1;jj<16;jj++) mx = fmaxf(mx, sc[jj]);
      mx = fmaxf(mx, __shfl_xor(mx, 1, 64));
      mx = fmaxf(mx, __shfl_xor(mx, 2, 64));
      float mnew = fmaxf(mrun, mx);
      float psum = 0.f;
      #pragma unroll
      for (int jj=0;jj<16;jj++){
        float p = __expf(sc[jj]-mnew);
        Ps[r*65 + seg*16 + jj] = p;
        psum += p;
      }
      psum += __shfl_xor(psum, 1, 64);
      psum += __shfl_xor(psum, 2, 64);
      float alpha = __expf(mrun - mnew);
      lrun = lrun*alpha + psum;
      mrun = mnew;
      #pragma unroll
      for (int i=0;i<16;i++) o[i] *= alpha;
      __syncthreads();
      #pragma unroll 4
      for (int j=0;j<64;j++){
        float pj = Ps[r*65 + j];
        uint4 u0 = *(const uint4*)&Vs[j*64 + seg*16];
        uint4 u1 = *(const uint4*)&Vs[j*64 + seg*16 + 8];
        o[ 0]=fmaf(pj,bflo(u0.x),o[ 0]); o[ 1]=fmaf(pj,bfhi(u0.x),o[ 1]);
        o[ 2]=fmaf(pj,bflo(u0.y),o[ 2]); o[ 3]=fmaf(pj,bfhi(u0.y),o[ 3]);
        o[ 4]=fmaf(pj,bflo(u0.z),o[ 4]); o[ 5]=fmaf(pj,bfhi(u0.z),o[ 5]);
        o[ 6]=fmaf(pj,bflo(u0.w),o[ 6]); o[ 7]=fmaf(pj,bfhi(u0.w),o[ 7]);
        o[ 8]=fmaf(pj,bflo(u1.x),o[ 8]); o[ 9]=fmaf(pj,bfhi(u1.x),o[ 9]);
        o[10]=fmaf(pj,bflo(u1.y),o[10]); o[11]=fmaf(pj,bfhi(u1.y),o[11]);
        o[12]=fmaf(pj,bflo(u1.z),o[12]); o[13]=fmaf(pj,bfhi(u1.z),o[13]);
        o[14]=fmaf(pj,bflo(u1.w),o[14]); o[15]=fmaf(pj,bfhi(u1.w),o[15]);
      }
    }
    float invl = 1.f/lrun;
    ushort* orow = ao + ((size_t)(b*SS + qt*64 + r))*DD + h*64 + seg*16;
    #pragma unroll
    for (int i=0;i<16;i++) orow[i] = f2bf(o[i]*invl);
    return;
  }

  // ------------------------------ casts ----------------------------------
  {
    int cbid = bid0 - 1056;
    const float* src; ushort* dst; int n;
    if (cbid < 1024)      { src = Wo32;  dst = Wob;  n = 1048576; }
    else if (cbid < 5120) { src = f1w32; dst = f1wb; n = 4194304; cbid -= 1024; }
    else                  { src = f2w32; dst = f2wb; n = 4194304; cbid -= 5120; }
    int i = (cbid*256 + t)*4;
    if (i >= n) return;
    float4 vv = *(const float4*)(src+i);
    ushort4 oo; oo.x=f2bf(vv.x); oo.y=f2bf(vv.y); oo.z=f2bf(vv.z); oo.w=f2bf(vv.w);
    *(ushort4*)(dst+i) = oo;
  }
}

// --------------------------------------------------------------- launch -----
extern "C" void kernel_launch(void* const* d_in, const int* in_sizes, int n_in,
                              void* d_out, int out_size, void* d_ws, size_t ws_size,
                              hipStream_t stream)
{
  const float* x   = (const float*)d_in[0];
  const float* n1w = (const float*)d_in[1];
  const float* Wq  = (const float*)d_in[2];
  const float* bq  = (const float*)d_in[3];
  const float* Wk  = (const float*)d_in[4];
  const float* bk  = (const float*)d_in[5];
  const float* Wv  = (const float*)d_in[6];
  const float* bv  = (const float*)d_in[7];
  const float* Wz  = (const float*)d_in[8];
  const float* bz  = (const float*)d_in[9];
  const float* Wg_ = (const float*)d_in[10];
  const float* bg  = (const float*)d_in[11];
  const float* gdw = (const float*)d_in[12];
  const float* gdb = (const float*)d_in[13];
  const float* guw = (const float*)d_in[14];
  const float* gub = (const float*)d_in[15];
  const float* Wo  = (const float*)d_in[16];
  const float* bo  = (const float*)d_in[17];
  const float* n2w = (const float*)d_in[18];
  const float* f1w = (const float*)d_in[19];
  const float* f1b = (const float*)d_in[20];
  const float* f2w = (const float*)d_in[21];
  const float* f2b = (const float*)d_in[22];

  char* ws = (char*)d_ws;
  const size_t MB = (size_t)1<<20;
  ushort* Wqb  = (ushort*)(ws +  0*MB);
  ushort* Wkb  = (ushort*)(ws +  2*MB);
  ushort* Wvb  = (ushort*)(ws +  4*MB);
  ushort* Wzb  = (ushort*)(ws +  6*MB);
  ushort* Wob  = (ushort*)(ws +  8*MB);
  ushort* Wgb  = (ushort*)(ws + 10*MB);
  ushort* gdwb = (ushort*)(ws + 12*MB);
  ushort* guwb = (ushort*)(ws + 12*MB + (512<<10));
  ushort* f1wb = (ushort*)(ws + 13*MB);
  ushort* f2wb = (ushort*)(ws + 21*MB);
  ushort* xn   = (ushort*)(ws + 29*MB);
  ushort* qb   = (ushort*)(ws + 37*MB);
  ushort* kb   = (ushort*)(ws + 45*MB);
  ushort* vb   = (ushort*)(ws + 53*MB);
  ushort* zb16 = (ushort*)(ws + 61*MB);
  ushort* ff1  = (ushort*)(ws + 37*MB);   // aliases qb..zb16 (dead by then)
  ushort* t1   = (ushort*)(ws + 69*MB);
  ushort* hseq = (ushort*)(ws + 70*MB);
  ushort* aob  = (ushort*)(ws + 78*MB);
  float*  zb32 = (float*) (ws + 86*MB);
  float*  yf   = (float*) (ws + 86*MB);   // aliases zb32 (dead after scan)
  float*  gm32 = (float*) (ws +102*MB);
  ushort* hst  = (ushort*)(ws +118*MB);   // 4 x 4096 bf16 ring (32 KB)
  ushort* yn = xn;

  // 0+1. fused: 7 weight casts + rmsnorm1 (one dispatch)
  prep_k<<<9472, 256, 0, stream>>>(Wq, Wqb, Wk, Wkb, Wv, Wvb, Wz, Wzb,
                                   Wg_, Wgb, gdw, gdwb, guw, guwb,
                                   x, n1w, xn);
  // 2. fused Q/K/V/Z projections (one dispatch, 1024 blocks)
  qkvz_k<<<dim3(32,8,4), 256, 0, stream>>>(xn, Wqb, Wkb, Wvb, Wzb,
                                           bq, bk, bv, bz,
                                           qb, kb, vb, zb16, zb32);
  // 3. gamma
  gemm_bt<ACT_RELU,EPI_B16><<<dim3(32,1), 256, 0, stream>>>(zb16, gdwb, gdb, 128, 1024, t1, nullptr, nullptr, nullptr, nullptr);
  gemm_bt<ACT_SIG ,EPI_F32><<<dim3(32,8), 256, 0, stream>>>(t1, guwb, gub, 1024, 128, nullptr, gm32, nullptr, nullptr, nullptr);
  // 4+5. fused: scan (blocks 0-31) || attention (32-1055) || casts (1056+)
  (void)hipMemsetAsync(hst, 0xFF, 32768, stream);
  fused_k<<<dim3(10272), 256, 0, stream>>>(Wgb, bg, zb32, gm32, hseq, hst,
                                           qb, kb, vb, aob,
                                           Wo, Wob, f1w, f1wb, f2w, f2wb);
  // 6. y = x + ao@Wo.T+bo + hseq
  gemm_bt<ACT_NONE,EPI_Y><<<dim3(32,8), 256, 0, stream>>>(aob, Wob, bo, 1024, 1024, nullptr, yf, x, hseq, nullptr);
  // 7. FFN + out
  rmsnorm_k<<<4096, 256, 0, stream>>>(yf, n2w, yn);
  gemm_bt<ACT_GELU,EPI_B16><<<dim3(32,32), 256, 0, stream>>>(yn, f1wb, f1b, 4096, 1024, ff1, nullptr, nullptr, nullptr, nullptr);
  gemm_bt<ACT_NONE,EPI_OUT><<<dim3(32,8), 256, 0, stream>>>(ff1, f2wb, f2b, 1024, 4096, nullptr, (float*)d_out, nullptr, nullptr, yf);
}

// Round 11
// 4359.447 us; speedup vs baseline: 2.1636x; 1.0013x over previous
//
#include <hip/hip_runtime.h>
#include <stdint.h>

#define DD 1024   // D
#define SS 1024   // S

typedef __attribute__((ext_vector_type(8))) __bf16 bf16x8;
typedef __attribute__((ext_vector_type(4))) float f32x4;

union Frag { uint4 u; bf16x8 b; };

__device__ __forceinline__ float bf2f(ushort u){ union{uint32_t i; float f;} c; c.i = ((uint32_t)u)<<16; return c.f; }
__device__ __forceinline__ float bflo(uint32_t p){ union{uint32_t i; float f;} c; c.i = p<<16; return c.f; }
__device__ __forceinline__ float bfhi(uint32_t p){ union{uint32_t i; float f;} c; c.i = p & 0xffff0000u; return c.f; }
__device__ __forceinline__ ushort f2bf(float f){
  union{float f; uint32_t u;} c; c.f = f;
  uint32_t u = c.u;
  return (ushort)((u + 0x7fffu + ((u>>16)&1u)) >> 16);   // RNE
}

// async global->LDS, 16B per lane. LDS dest must be wave-uniform base +
// lane*16B (our staging layout already is). Guide: width=16 vs reg-staging
// = 874 vs 646 TF at the same 128^2 tile (m151/m97).
__device__ __forceinline__ void gload_lds16(const ushort* g, ushort* l) {
  __builtin_amdgcn_global_load_lds(
      (const __attribute__((address_space(1))) void*)g,
      (__attribute__((address_space(3))) void*)l, 16, 0, 0);
}

// ---------------------------------------------- fused casts + rmsnorm1 ------
// blocks 0..5375: cast 7 weight arrays fp32->bf16 (Wq,Wk,Wv,Wz,Wg,gdw,guw)
// blocks 5376..9471: rmsnorm(x) -> xn   (independent of the casts)
__global__ __launch_bounds__(256) void prep_k(
    const float* __restrict__ Wq,  ushort* __restrict__ Wqb,
    const float* __restrict__ Wk,  ushort* __restrict__ Wkb,
    const float* __restrict__ Wv,  ushort* __restrict__ Wvb,
    const float* __restrict__ Wz,  ushort* __restrict__ Wzb,
    const float* __restrict__ Wg,  ushort* __restrict__ Wgb,
    const float* __restrict__ gdw, ushort* __restrict__ gdwb,
    const float* __restrict__ guw, ushort* __restrict__ guwb,
    const float* __restrict__ X,   const float* __restrict__ n1w,
    ushort* __restrict__ xn)
{
  const int bid = blockIdx.x, t = threadIdx.x;
  if (bid < 5376) {
    int cbid = bid;
    const float* src; ushort* dst; int n;
    if (cbid < 1024)      { src = Wq;  dst = Wqb;  n = 1048576; }
    else if (cbid < 2048) { src = Wk;  dst = Wkb;  n = 1048576; cbid -= 1024; }
    else if (cbid < 3072) { src = Wv;  dst = Wvb;  n = 1048576; cbid -= 2048; }
    else if (cbid < 4096) { src = Wz;  dst = Wzb;  n = 1048576; cbid -= 3072; }
    else if (cbid < 5120) { src = Wg;  dst = Wgb;  n = 1048576; cbid -= 4096; }
    else if (cbid < 5248) { src = gdw; dst = gdwb; n = 131072;  cbid -= 5120; }
    else                  { src = guw; dst = guwb; n = 131072;  cbid -= 5248; }
    int i = (cbid*256 + t)*4;
    if (i >= n) return;
    float4 v = *(const float4*)(src+i);
    ushort4 o; o.x=f2bf(v.x); o.y=f2bf(v.y); o.z=f2bf(v.z); o.w=f2bf(v.w);
    *(ushort4*)(dst+i) = o;
    return;
  }
  // rmsnorm
  const int row = bid - 5376;
  const float* x = X + (size_t)row*DD;
  float xs[4]; float s = 0.f;
  #pragma unroll
  for (int i=0;i<4;i++){ float v = x[t + i*256]; xs[i]=v; s += v*v; }
  #pragma unroll
  for (int off=32; off>0; off>>=1) s += __shfl_xor(s, off, 64);
  __shared__ float sred[4];
  if ((t&63)==0) sred[t>>6] = s;
  __syncthreads();
  s = sred[0]+sred[1]+sred[2]+sred[3];
  float inv = 1.f/(sqrtf(s)*0.03125f + 1e-6f);   // /sqrt(1024), + eps
  #pragma unroll
  for (int i=0;i<4;i++){
    int c2 = t + i*256;
    xn[(size_t)row*DD + c2] = f2bf(xs[i]*inv*n1w[c2]);
  }
}

// ---------------------------------------------------------------- rmsnorm ---
__global__ __launch_bounds__(256) void rmsnorm_k(const float* __restrict__ X,
    const float* __restrict__ w, ushort* __restrict__ out)
{
  const int row = blockIdx.x, t = threadIdx.x;
  const float* x = X + (size_t)row*DD;
  float xs[4]; float s = 0.f;
  #pragma unroll
  for (int i=0;i<4;i++){ float v = x[t + i*256]; xs[i]=v; s += v*v; }
  #pragma unroll
  for (int off=32; off>0; off>>=1) s += __shfl_xor(s, off, 64);
  __shared__ float sred[4];
  if ((t&63)==0) sred[t>>6] = s;
  __syncthreads();
  s = sred[0]+sred[1]+sred[2]+sred[3];
  float inv = 1.f/(sqrtf(s)*0.03125f + 1e-6f);   // /sqrt(1024), + eps
  #pragma unroll
  for (int i=0;i<4;i++){
    int c2 = t + i*256;
    out[(size_t)row*DD + c2] = f2bf(xs[i]*inv*w[c2]);
  }
}

// ---------------------------------------------------------- MFMA GEMM (BT) --
enum { ACT_NONE=0, ACT_RELU=1, ACT_SIG=2, ACT_GELU=3 };
enum { EPI_B16=0, EPI_DUAL=1, EPI_F32=2, EPI_Y=3, EPI_OUT=4 };

template<int ACT, int EPI>
__global__ __launch_bounds__(256) void gemm_bt(
    const ushort* __restrict__ A, const ushort* __restrict__ W,
    const float* __restrict__ bias, int N, int K,
    ushort* __restrict__ Ob, float* __restrict__ Of,
    const float* __restrict__ X32, const ushort* __restrict__ H16,
    const float* __restrict__ Yf)
{
  __shared__ __align__(16) ushort At[128*32];
  __shared__ __align__(16) ushort Wt[128*32];
  const int tid = threadIdx.x;
  const int wave = tid >> 6, lane = tid & 63;
  const int quad = lane >> 4, l16 = lane & 15;
  const int wr = wave >> 1, wc = wave & 1;
  const int m0 = blockIdx.x * 128, n0 = blockIdx.y * 128;

  f32x4 acc[4][4];
  const f32x4 vz = {0.f,0.f,0.f,0.f};
  #pragma unroll
  for (int i=0;i<4;i++)
    #pragma unroll
    for (int j=0;j<4;j++) acc[i][j] = vz;

  const ushort* gA = A + (size_t)(m0 + wave*32 + (lane>>2))*K + (lane&3)*8;
  const ushort* gW = W + (size_t)(n0 + wave*32 + (lane>>2))*K + (lane&3)*8;
  ushort* lA = At + wave*1024 + lane*8;
  ushort* lW = Wt + wave*1024 + lane*8;

  for (int ko = 0; ko < K; ko += 32) {
    __syncthreads();                      // prior compute done reading LDS
    gload_lds16(gA + ko,                lA);
    gload_lds16(gA + ko + (size_t)16*K, lA + 512);
    gload_lds16(gW + ko,                lW);
    gload_lds16(gW + ko + (size_t)16*K, lW + 512);
    __syncthreads();                      // vmcnt(0) drained -> LDS ready
    Frag af[4], bfr[4];
    #pragma unroll
    for (int mi=0;mi<4;mi++)
      af[mi].u = *(const uint4*)&At[(wr*64 + mi*16 + l16)*32 + quad*8];
    #pragma unroll
    for (int ni=0;ni<4;ni++)
      bfr[ni].u = *(const uint4*)&Wt[(wc*64 + ni*16 + l16)*32 + quad*8];
    #pragma unroll
    for (int mi=0;mi<4;mi++)
      #pragma unroll
      for (int ni=0;ni<4;ni++)
        acc[mi][ni] = __builtin_amdgcn_mfma_f32_16x16x32_bf16(af[mi].b, bfr[ni].b, acc[mi][ni], 0,0,0);
  }

  float bia[4];
  #pragma unroll
  for (int ni=0;ni<4;ni++) bia[ni] = bias[n0 + wc*64 + ni*16 + l16];
  #pragma unroll
  for (int mi=0;mi<4;mi++) {
    const int row0 = m0 + wr*64 + mi*16 + quad*4;
    #pragma unroll
    for (int ni=0;ni<4;ni++) {
      const int col = n0 + wc*64 + ni*16 + l16;
      #pragma unroll
      for (int r=0;r<4;r++) {
        float vx = acc[mi][ni][r] + bia[ni];
        if (ACT == ACT_RELU) vx = fmaxf(vx, 0.f);
        else if (ACT == ACT_SIG) {
          vx = 1.f/(1.f+__expf(-vx));
          vx = fminf(fmaxf(vx, 1e-6f), 1.f-1e-6f);
        } else if (ACT == ACT_GELU) {
          float ci = 0.7978845608028654f*(vx + 0.044715f*vx*vx*vx);
          float th = 1.f - 2.f/(1.f + __expf(2.f*ci));
          vx = 0.5f*vx*(1.f+th);
        }
        size_t idx = (size_t)(row0 + r)*N + col;
        if (EPI == EPI_B16)      Ob[idx] = f2bf(vx);
        else if (EPI == EPI_DUAL){ Ob[idx] = f2bf(vx); Of[idx] = vx; }
        else if (EPI == EPI_F32)  Of[idx] = vx;
        else if (EPI == EPI_Y)    Of[idx] = vx + X32[idx] + bf2f(H16[idx]);
        else                      Of[idx] = vx + Yf[idx];
      }
    }
  }
}

// --------------------------------------------- fused Q/K/V/Z projections ----
// grid (32, 8, 4): z selects the weight/bias/output set. Identical GEMM body
// (ACT_NONE); z==3 (Z-proj) additionally writes the fp32 copy (EPI_DUAL).
__global__ __launch_bounds__(256) void qkvz_k(
    const ushort* __restrict__ A,
    const ushort* __restrict__ Wqb, const ushort* __restrict__ Wkb,
    const ushort* __restrict__ Wvb, const ushort* __restrict__ Wzb,
    const float* __restrict__ bq, const float* __restrict__ bk,
    const float* __restrict__ bv, const float* __restrict__ bz,
    ushort* __restrict__ qb, ushort* __restrict__ kb,
    ushort* __restrict__ vb, ushort* __restrict__ zb16,
    float* __restrict__ zb32)
{
  const int proj = blockIdx.z;
  const ushort* W; const float* bias; ushort* Ob; bool dual = false;
  if (proj == 0)      { W = Wqb; bias = bq; Ob = qb; }
  else if (proj == 1) { W = Wkb; bias = bk; Ob = kb; }
  else if (proj == 2) { W = Wvb; bias = bv; Ob = vb; }
  else                { W = Wzb; bias = bz; Ob = zb16; dual = true; }
  const int N = 1024, K = 1024;

  __shared__ __align__(16) ushort At[128*32];
  __shared__ __align__(16) ushort Wt[128*32];
  const int tid = threadIdx.x;
  const int wave = tid >> 6, lane = tid & 63;
  const int quad = lane >> 4, l16 = lane & 15;
  const int wr = wave >> 1, wc = wave & 1;
  const int m0 = blockIdx.x * 128, n0 = blockIdx.y * 128;

  f32x4 acc[4][4];
  const f32x4 vz = {0.f,0.f,0.f,0.f};
  #pragma unroll
  for (int i=0;i<4;i++)
    #pragma unroll
    for (int j=0;j<4;j++) acc[i][j] = vz;

  const ushort* gA = A + (size_t)(m0 + wave*32 + (lane>>2))*K + (lane&3)*8;
  const ushort* gW = W + (size_t)(n0 + wave*32 + (lane>>2))*K + (lane&3)*8;
  ushort* lA = At + wave*1024 + lane*8;
  ushort* lW = Wt + wave*1024 + lane*8;

  for (int ko = 0; ko < K; ko += 32) {
    __syncthreads();
    gload_lds16(gA + ko,                lA);
    gload_lds16(gA + ko + (size_t)16*K, lA + 512);
    gload_lds16(gW + ko,                lW);
    gload_lds16(gW + ko + (size_t)16*K, lW + 512);
    __syncthreads();
    Frag af[4], bfr[4];
    #pragma unroll
    for (int mi=0;mi<4;mi++)
      af[mi].u = *(const uint4*)&At[(wr*64 + mi*16 + l16)*32 + quad*8];
    #pragma unroll
    for (int ni=0;ni<4;ni++)
      bfr[ni].u = *(const uint4*)&Wt[(wc*64 + ni*16 + l16)*32 + quad*8];
    #pragma unroll
    for (int mi=0;mi<4;mi++)
      #pragma unroll
      for (int ni=0;ni<4;ni++)
        acc[mi][ni] = __builtin_amdgcn_mfma_f32_16x16x32_bf16(af[mi].b, bfr[ni].b, acc[mi][ni], 0,0,0);
  }

  float bia[4];
  #pragma unroll
  for (int ni=0;ni<4;ni++) bia[ni] = bias[n0 + wc*64 + ni*16 + l16];
  #pragma unroll
  for (int mi=0;mi<4;mi++) {
    const int row0 = m0 + wr*64 + mi*16 + quad*4;
    #pragma unroll
    for (int ni=0;ni<4;ni++) {
      const int col = n0 + wc*64 + ni*16 + l16;
      #pragma unroll
      for (int r=0;r<4;r++) {
        float vx = acc[mi][ni][r] + bia[ni];
        size_t idx = (size_t)(row0 + r)*N + col;
        Ob[idx] = f2bf(vx);
        if (dual) zb32[idx] = vx;
      }
    }
  }
}

// ------------------------------------------------- fused scan+attn+casts ----
// Blocks 0..31: the PROVEN R10 scan (byte-identical protocol). Blocks
// 32..1055: attention. Blocks 1056..10271: Wo/f1w/f2w casts. See R16 notes:
// lockstep barriers bound concurrent atomic bursts; all protocol "upgrades"
// (R12/R13/R14/R15) lost to this structure.
__global__ __launch_bounds__(256) void fused_k(
    const ushort* __restrict__ Wgb, const float* __restrict__ bg,
    const float* __restrict__ z32, const float* __restrict__ gm32,
    ushort* __restrict__ hseq, ushort* __restrict__ hstate,
    const ushort* __restrict__ q, const ushort* __restrict__ k,
    const ushort* __restrict__ v, ushort* __restrict__ ao,
    const float* __restrict__ Wo32, ushort* __restrict__ Wob,
    const float* __restrict__ f1w32, ushort* __restrict__ f1wb,
    const float* __restrict__ f2w32, ushort* __restrict__ f2wb)
{
  __shared__ __align__(16) char smem[33024];   // attn: 8K Ks + 8K Vs + 16.6K Ps
  const int bid0 = blockIdx.x;                 // scan: 8K Hs + 2.5K redbuf
  const int t = threadIdx.x;

  if (bid0 < 32) {
    // ---------------- scan (R10 verbatim, smem-overlaid) ----------------
    const int blk = bid0;
    const int wave = t>>6, lane = t&63, quad = lane>>4, c = lane&15;
    const int mt = wave & 1, kh = wave >> 1;
    const int nbase = blk*32 + mt*16;
    const bool epi = (kh == 0) && (c < 4);
    const int n0w = nbase + quad*4;
    Frag a[16];                                   // Wg A-frags, loop-invariant
    {
      const ushort* wrow = Wgb + (size_t)(nbase + c)*DD + kh*512 + quad*8;
      #pragma unroll
      for (int kt=0;kt<16;kt++) a[kt].u = *(const uint4*)(wrow + kt*32);
    }
    float bgv[4];
    #pragma unroll
    for (int r=0;r<4;r++) bgv[r] = bg[nbase + quad*4 + r];
    ushort* Hs = (ushort*)smem;                   // [4096]
    float*  redbuf = (float*)(smem + 8192);       // [2][64][5]
    const int qi = (c*1024 + n0w) >> 2;           // this lane's h slice (qword)
    int gmax = 256;                               // poll budget; 0 after trip

    float4 znx = {0,0,0,0}, gnx = {0,0,0,0};
    if (epi) {
      znx = *(const float4*)(z32  + ((size_t)c*SS + 0)*DD + n0w);
      gnx = *(const float4*)(gm32 + ((size_t)c*SS + 0)*DD + n0w);
    }

    for (int st=0; st<SS; st++) {
      if (st > 0) {
        const uint64_t* hrd = (const uint64_t*)(hstate + ((st+3)&3)*4096);
        uint64_t v0,v1,v2,v3;
        int guard = 0;
        for (;;) {
          v0 = __hip_atomic_load(hrd + t*4 + 0, __ATOMIC_RELAXED, __HIP_MEMORY_SCOPE_AGENT);
          v1 = __hip_atomic_load(hrd + t*4 + 1, __ATOMIC_RELAXED, __HIP_MEMORY_SCOPE_AGENT);
          v2 = __hip_atomic_load(hrd + t*4 + 2, __ATOMIC_RELAXED, __HIP_MEMORY_SCOPE_AGENT);
          v3 = __hip_atomic_load(hrd + t*4 + 3, __ATOMIC_RELAXED, __HIP_MEMORY_SCOPE_AGENT);
          bool ok = ((uint32_t)v0 != 0xFFFFFFFFu) & ((uint32_t)(v0>>32) != 0xFFFFFFFFu)
                  & ((uint32_t)v1 != 0xFFFFFFFFu) & ((uint32_t)(v1>>32) != 0xFFFFFFFFu)
                  & ((uint32_t)v2 != 0xFFFFFFFFu) & ((uint32_t)(v2>>32) != 0xFFFFFFFFu)
                  & ((uint32_t)v3 != 0xFFFFFFFFu) & ((uint32_t)(v3>>32) != 0xFFFFFFFFu);
          if (ok) break;
          if (++guard > gmax) { gmax = 0; break; }  // fail fast+loud (NaN)
          __builtin_amdgcn_s_sleep(1);
        }
        if (epi) {
          uint64_t* rst = (uint64_t*)(hstate + ((st+2)&3)*4096);
          __hip_atomic_store(rst + qi, 0xFFFFFFFFFFFFFFFFull,
                             __ATOMIC_RELAXED, __HIP_MEMORY_SCOPE_AGENT);
        }
        uint64_t* hsd = (uint64_t*)Hs;
        hsd[t*4+0]=v0; hsd[t*4+1]=v1; hsd[t*4+2]=v2; hsd[t*4+3]=v3;
      }
      float4 zc = znx, gc = gnx;
      if (epi && (st+1 < SS)) {
        znx = *(const float4*)(z32  + ((size_t)c*SS + (st+1))*DD + n0w);
        gnx = *(const float4*)(gm32 + ((size_t)c*SS + (st+1))*DD + n0w);
      }
      if (st > 0) {
        asm volatile("s_waitcnt lgkmcnt(0)\ns_barrier" ::: "memory");
      }
      f32x4 acc = {0.f,0.f,0.f,0.f};
      if (st > 0) {
        f32x4 acc1 = {0.f,0.f,0.f,0.f};
        const uint4 z4 = make_uint4(0u,0u,0u,0u);
        #pragma unroll
        for (int kt=0;kt<16;kt+=2) {
          Frag b0, b1;
          b0.u = (c<4) ? *(const uint4*)&Hs[c*1024 + kh*512 + (kt  )*32 + quad*8] : z4;
          b1.u = (c<4) ? *(const uint4*)&Hs[c*1024 + kh*512 + (kt+1)*32 + quad*8] : z4;
          acc  = __builtin_amdgcn_mfma_f32_16x16x32_bf16(a[kt  ].b, b0.b, acc,  0,0,0);
          acc1 = __builtin_amdgcn_mfma_f32_16x16x32_bf16(a[kt+1].b, b1.b, acc1, 0,0,0);
        }
        #pragma unroll
        for (int r=0;r<4;r++) acc[r] += acc1[r];
      }
      if (kh == 1) {
        #pragma unroll
        for (int r=0;r<4;r++) redbuf[(mt*64 + lane)*5 + r] = acc[r];
      }
      asm volatile("s_waitcnt lgkmcnt(0)\ns_barrier" ::: "memory");
      if (epi) {
        ushort hb[4];
        float zr[4] = {zc.x, zc.y, zc.z, zc.w};
        float gr[4] = {gc.x, gc.y, gc.z, gc.w};
        #pragma unroll
        for (int r=0;r<4;r++) {
          float g = acc[r] + redbuf[(mt*64 + lane)*5 + r] + bgv[r];
          g = 1.f/(1.f+__expf(-g));
          float hp = (st>0) ? bf2f(Hs[c*1024 + n0w + r]) : 0.f;
          hb[r] = f2bf(zr[r]*g + gr[r]*hp);
        }
        uint32_t p0 = (uint32_t)hb[0] | ((uint32_t)hb[1]<<16);
        uint32_t p1 = (uint32_t)hb[2] | ((uint32_t)hb[3]<<16);
        uint64_t pk = ((uint64_t)p1<<32) | (uint64_t)p0;
        uint64_t* hwd = (uint64_t*)(hstate + (st&3)*4096);
        __hip_atomic_store(hwd + qi, pk, __ATOMIC_RELAXED, __HIP_MEMORY_SCOPE_AGENT);
        uint2* sq = (uint2*)(hseq + ((size_t)c*SS + st)*DD + n0w);
        *sq = make_uint2(p0, p1);          // cached store: stays in L2
      }
      asm volatile("s_waitcnt lgkmcnt(0)\ns_barrier" ::: "memory");  // lockstep
    }
    return;
  }

  if (bid0 < 1056) {
    // ------------------------- attention (verbatim) ----------------------
    const int abid = bid0 - 32;
    const int qt = abid & 15, bh = abid >> 4;
    const int b = bh >> 4, h = bh & 15;
    const int r = t >> 2, seg = t & 3;
    ushort* Ks = (ushort*)smem;                  // [64*64]
    ushort* Vs = (ushort*)(smem + 8192);         // [64*64]
    float*  Ps = (float*)(smem + 16384);         // [64*65]
    const ushort* qrow = q + ((size_t)(b*SS + qt*64 + r))*DD + h*64;
    float qr[64];
    #pragma unroll
    for (int i=0;i<64;i+=8){
      uint4 u = *(const uint4*)(qrow + i);
      qr[i+0]=bflo(u.x); qr[i+1]=bfhi(u.x); qr[i+2]=bflo(u.y); qr[i+3]=bfhi(u.y);
      qr[i+4]=bflo(u.z); qr[i+5]=bfhi(u.z); qr[i+6]=bflo(u.w); qr[i+7]=bfhi(u.w);
    }
    float o[16];
    #pragma unroll
    for (int i=0;i<16;i++) o[i]=0.f;
    float mrun = -1e30f, lrun = 0.f;
    const int jrow = t >> 3, jch = t & 7;
    for (int kt=0; kt<16; kt++) {
      __syncthreads();
      const ushort* kg = k + ((size_t)(b*SS + kt*64))*DD + h*64;
      const ushort* vg = v + ((size_t)(b*SS + kt*64))*DD + h*64;
      #pragma unroll
      for (int part=0; part<2; part++){
        int j = jrow + part*32;
        *(uint4*)&Ks[j*64 + jch*8] = *(const uint4*)(kg + (size_t)j*DD + jch*8);
        *(uint4*)&Vs[j*64 + jch*8] = *(const uint4*)(vg + (size_t)j*DD + jch*8);
      }
      __syncthreads();
      float sc[16];
      #pragma unroll
      for (int jj=0;jj<16;jj++){
        int j = seg*16 + jj;
        float s_ = 0.f;
        #pragma unroll
        for (int i=0;i<64;i+=8){
          uint4 u = *(const uint4*)&Ks[j*64+i];
          s_ = fmaf(qr[i+0], bflo(u.x), s_); s_ = fmaf(qr[i+1], bfhi(u.x), s_);
          s_ = fmaf(qr[i+2], bflo(u.y), s_); s_ = fmaf(qr[i+3], bfhi(u.y), s_);
          s_ = fmaf(qr[i+4], bflo(u.z), s_); s_ = fmaf(qr[i+5], bfhi(u.z), s_);
          s_ = fmaf(qr[i+6], bflo(u.w), s_); s_ = fmaf(qr[i+7], bfhi(u.w), s_);
        }
        sc[jj] = s_ * 0.125f;
      }
      float mx = sc[0];
      #pragma unroll
      for (int jj=1;jj<16;jj++) mx = fmaxf(mx, sc[jj]);
      mx = fmaxf(mx, __shfl_xor(mx, 1, 64));
      mx = fmaxf(mx, __shfl_xor(mx, 2, 64));
      float mnew = fmaxf(mrun, mx);
      float psum = 0.f;
      #pragma unroll
      for (int jj=0;jj<16;jj++){
        float p = __expf(sc[jj]-mnew);
        Ps[r*65 + seg*16 + jj] = p;
        psum += p;
      }
      psum += __shfl_xor(psum, 1, 64);
      psum += __shfl_xor(psum, 2, 64);
      float alpha = __expf(mrun - mnew);
      lrun = lrun*alpha + psum;
      mrun = mnew;
      #pragma unroll
      for (int i=0;i<16;i++) o[i] *= alpha;
      __syncthreads();
      #pragma unroll 4
      for (int j=0;j<64;j++){
        float pj = Ps[r*65 + j];
        uint4 u0 = *(const uint4*)&Vs[j*64 + seg*16];
        uint4 u1 = *(const uint4*)&Vs[j*64 + seg*16 + 8];
        o[ 0]=fmaf(pj,bflo(u0.x),o[ 0]); o[ 1]=fmaf(pj,bfhi(u0.x),o[ 1]);
        o[ 2]=fmaf(pj,bflo(u0.y),o[ 2]); o[ 3]=fmaf(pj,bfhi(u0.y),o[ 3]);
        o[ 4]=fmaf(pj,bflo(u0.z),o[ 4]); o[ 5]=fmaf(pj,bfhi(u0.z),o[ 5]);
        o[ 6]=fmaf(pj,bflo(u0.w),o[ 6]); o[ 7]=fmaf(pj,bfhi(u0.w),o[ 7]);
        o[ 8]=fmaf(pj,bflo(u1.x),o[ 8]); o[ 9]=fmaf(pj,bfhi(u1.x),o[ 9]);
        o[10]=fmaf(pj,bflo(u1.y),o[10]); o[11]=fmaf(pj,bfhi(u1.y),o[11]);
        o[12]=fmaf(pj,bflo(u1.z),o[12]); o[13]=fmaf(pj,bfhi(u1.z),o[13]);
        o[14]=fmaf(pj,bflo(u1.w),o[14]); o[15]=fmaf(pj,bfhi(u1.w),o[15]);
      }
    }
    float invl = 1.f/lrun;
    ushort* orow = ao + ((size_t)(b*SS + qt*64 + r))*DD + h*64 + seg*16;
    #pragma unroll
    for (int i=0;i<16;i++) orow[i] = f2bf(o[i]*invl);
    return;
  }

  // ------------------------------ casts ----------------------------------
  {
    int cbid = bid0 - 1056;
    const float* src; ushort* dst; int n;
    if (cbid < 1024)      { src = Wo32;  dst = Wob;  n = 1048576; }
    else if (cbid < 5120) { src = f1w32; dst = f1wb; n = 4194304; cbid -= 1024; }
    else                  { src = f2w32; dst = f2wb; n = 4194304; cbid -= 5120; }
    int i = (cbid*256 + t)*4;
    if (i >= n) return;
    float4 vv = *(const float4*)(src+i);
    ushort4 oo; oo.x=f2bf(vv.x); oo.y=f2bf(vv.y); oo.z=f2bf(vv.z); oo.w=f2bf(vv.w);
    *(ushort4*)(dst+i) = oo;
  }
}

// --------------------------------------------------------------- launch -----
extern "C" void kernel_launch(void* const* d_in, const int* in_sizes, int n_in,
                              void* d_out, int out_size, void* d_ws, size_t ws_size,
                              hipStream_t stream)
{
  const float* x   = (const float*)d_in[0];
  const float* n1w = (const float*)d_in[1];
  const float* Wq  = (const float*)d_in[2];
  const float* bq  = (const float*)d_in[3];
  const float* Wk  = (const float*)d_in[4];
  const float* bk  = (const float*)d_in[5];
  const float* Wv  = (const float*)d_in[6];
  const float* bv  = (const float*)d_in[7];
  const float* Wz  = (const float*)d_in[8];
  const float* bz  = (const float*)d_in[9];
  const float* Wg_ = (const float*)d_in[10];
  const float* bg  = (const float*)d_in[11];
  const float* gdw = (const float*)d_in[12];
  const float* gdb = (const float*)d_in[13];
  const float* guw = (const float*)d_in[14];
  const float* gub = (const float*)d_in[15];
  const float* Wo  = (const float*)d_in[16];
  const float* bo  = (const float*)d_in[17];
  const float* n2w = (const float*)d_in[18];
  const float* f1w = (const float*)d_in[19];
  const float* f1b = (const float*)d_in[20];
  const float* f2w = (const float*)d_in[21];
  const float* f2b = (const float*)d_in[22];

  char* ws = (char*)d_ws;
  const size_t MB = (size_t)1<<20;
  ushort* Wqb  = (ushort*)(ws +  0*MB);
  ushort* Wkb  = (ushort*)(ws +  2*MB);
  ushort* Wvb  = (ushort*)(ws +  4*MB);
  ushort* Wzb  = (ushort*)(ws +  6*MB);
  ushort* Wob  = (ushort*)(ws +  8*MB);
  ushort* Wgb  = (ushort*)(ws + 10*MB);
  ushort* gdwb = (ushort*)(ws + 12*MB);
  ushort* guwb = (ushort*)(ws + 12*MB + (512<<10));
  ushort* f1wb = (ushort*)(ws + 13*MB);
  ushort* f2wb = (ushort*)(ws + 21*MB);
  ushort* xn   = (ushort*)(ws + 29*MB);
  ushort* qb   = (ushort*)(ws + 37*MB);
  ushort* kb   = (ushort*)(ws + 45*MB);
  ushort* vb   = (ushort*)(ws + 53*MB);
  ushort* zb16 = (ushort*)(ws + 61*MB);
  ushort* ff1  = (ushort*)(ws + 37*MB);   // aliases qb..zb16 (dead by then)
  ushort* t1   = (ushort*)(ws + 69*MB);
  ushort* hseq = (ushort*)(ws + 70*MB);
  ushort* aob  = (ushort*)(ws + 78*MB);
  float*  zb32 = (float*) (ws + 86*MB);
  float*  yf   = (float*) (ws + 86*MB);   // aliases zb32 (dead after scan)
  float*  gm32 = (float*) (ws +102*MB);
  ushort* hst  = (ushort*)(ws +118*MB);   // 4 x 4096 bf16 ring (32 KB)
  ushort* yn = xn;

  // 0+1. fused: 7 weight casts + rmsnorm1 (one dispatch)
  prep_k<<<9472, 256, 0, stream>>>(Wq, Wqb, Wk, Wkb, Wv, Wvb, Wz, Wzb,
                                   Wg_, Wgb, gdw, gdwb, guw, guwb,
                                   x, n1w, xn);
  // 2. fused Q/K/V/Z projections (one dispatch, 1024 blocks)
  qkvz_k<<<dim3(32,8,4), 256, 0, stream>>>(xn, Wqb, Wkb, Wvb, Wzb,
                                           bq, bk, bv, bz,
                                           qb, kb, vb, zb16, zb32);
  // 3. gamma
  gemm_bt<ACT_RELU,EPI_B16><<<dim3(32,1), 256, 0, stream>>>(zb16, gdwb, gdb, 128, 1024, t1, nullptr, nullptr, nullptr, nullptr);
  gemm_bt<ACT_SIG ,EPI_F32><<<dim3(32,8), 256, 0, stream>>>(t1, guwb, gub, 1024, 128, nullptr, gm32, nullptr, nullptr, nullptr);
  // 4+5. fused: scan (blocks 0-31) || attention (32-1055) || casts (1056+)
  (void)hipMemsetAsync(hst, 0xFF, 32768, stream);
  fused_k<<<dim3(10272), 256, 0, stream>>>(Wgb, bg, zb32, gm32, hseq, hst,
                                           qb, kb, vb, aob,
                                           Wo, Wob, f1w, f1wb, f2w, f2wb);
  // 6. y = x + ao@Wo.T+bo + hseq
  gemm_bt<ACT_NONE,EPI_Y><<<dim3(32,8), 256, 0, stream>>>(aob, Wob, bo, 1024, 1024, nullptr, yf, x, hseq, nullptr);
  // 7. FFN + out
  rmsnorm_k<<<4096, 256, 0, stream>>>(yf, n2w, yn);
  gemm_bt<ACT_GELU,EPI_B16><<<dim3(32,32), 256, 0, stream>>>(yn, f1wb, f1b, 4096, 1024, ff1, nullptr, nullptr, nullptr, nullptr);
  gemm_bt<ACT_NONE,EPI_OUT><<<dim3(32,8), 256, 0, stream>>>(ff1, f2wb, f2b, 1024, 4096, nullptr, (float*)d_out, nullptr, nullptr, yf);
}